// Round 9
// baseline (364.429 us; speedup 1.0000x reference)
//
#include <hip/hip_runtime.h>
#include <math.h>

#define DIM 512
#define HEADS 8
#define QL 225
#define VS 196
#define BATCH 4
#define EPS_BN 1e-5f

typedef __attribute__((ext_vector_type(8))) short bf16x8;
typedef __attribute__((ext_vector_type(4))) float f32x4;

// ---------------- wave (64-lane) reductions ----------------
__device__ __forceinline__ float waveMax(float v) {
#pragma unroll
    for (int o = 32; o; o >>= 1) v = fmaxf(v, __shfl_xor(v, o, 64));
    return v;
}
__device__ __forceinline__ float waveSum(float v) {
#pragma unroll
    for (int o = 32; o; o >>= 1) v += __shfl_xor(v, o, 64);
    return v;
}

// ---------------- fp32 -> bf16 pack helpers ----------------
__device__ __forceinline__ unsigned cvt_pk_bf16(float lo, float hi) {
    unsigned r;
    asm("v_cvt_pk_bf16_f32 %0, %1, %2" : "=v"(r) : "v"(lo), "v"(hi));
    return r;
}
__device__ __forceinline__ uint4 ld_cvt8(const float* p) {
    float4 x = *(const float4*)p;
    float4 y = *(const float4*)(p + 4);
    uint4 r;
    r.x = cvt_pk_bf16(x.x, x.y);
    r.y = cvt_pk_bf16(x.z, x.w);
    r.z = cvt_pk_bf16(y.x, y.y);
    r.w = cvt_pk_bf16(y.z, y.w);
    return r;
}

// ---------------- multi-job bf16-MFMA GEMM (N=K=512): Out = scale*A@W^T (+bias)(relu)(+Add) ----
// Tile 64x64, BK=64, 4 waves in 2x2. DOUBLE-BUFFERED LDS: one barrier per K-iter;
// next iteration's global loads issue before this iteration's MFMA.
struct GJob {
    const float* A; const float* W; const float* bias; const float* Add; float* Out;
    long aBS, aOff, addBS, addOff;
    int aRows, addRows, M, relu;
    float scale; int pad0, pad1, pad2;
};
struct GJobs { GJob j[4]; };

template<int LAYER>
__global__ __launch_bounds__(256) void gemm_multi(GJobs jobs) {
    const GJob J = jobs.j[blockIdx.z];
    const int bm = blockIdx.y * 64, bn = blockIdx.x * 64;
    if (bm >= J.M) return;
    __shared__ __align__(16) ushort As[2][64][72];
    __shared__ __align__(16) ushort Bs[2][64][72];
    const int tid = threadIdx.x;
    const int srow = tid >> 2, skq = tid & 3;   // staging: row 0..63, 16-k chunk
    const float* ap = nullptr;
    {
        int m = bm + srow;
        if (m < J.M) { int bb = m / J.aRows; int r = m - bb * J.aRows;
                       ap = J.A + bb * J.aBS + J.aOff + (long)r * 512 + skq * 16; }
    }
    const float* bp = J.W + (long)(bn + srow) * 512 + skq * 16;

    const int lane = tid & 63, wid = tid >> 6;
    const int wr = wid >> 1, wc = wid & 1;      // 2x2 wave grid of 32x32 tiles
    const int lr = lane & 15, kg = lane >> 4;

    f32x4 acc[2][2] = {};

    // preload + stage kt = 0 into buffer 0
    uint4 a01 = {0u,0u,0u,0u}, a23 = {0u,0u,0u,0u};
    if (ap) { a01 = ld_cvt8(ap); a23 = ld_cvt8(ap + 8); }
    uint4 b01 = ld_cvt8(bp), b23 = ld_cvt8(bp + 8);
    *(uint4*)&As[0][srow][skq * 16]     = a01;
    *(uint4*)&As[0][srow][skq * 16 + 8] = a23;
    *(uint4*)&Bs[0][srow][skq * 16]     = b01;
    *(uint4*)&Bs[0][srow][skq * 16 + 8] = b23;
    __syncthreads();

#pragma unroll
    for (int it = 0; it < 8; it++) {
        const int cur = it & 1;
        // issue next iteration's global loads (latency hidden under MFMA below)
        if (it < 7) {
            const int kt = (it + 1) * 64;
            if (ap) { a01 = ld_cvt8(ap + kt); a23 = ld_cvt8(ap + kt + 8); }
            b01 = ld_cvt8(bp + kt); b23 = ld_cvt8(bp + kt + 8);
        }
        bf16x8 a[2][2], bb[2][2];
#pragma unroll
        for (int i = 0; i < 2; i++)
#pragma unroll
            for (int kf = 0; kf < 2; kf++)
                a[i][kf] = *(const bf16x8*)&As[cur][wr * 32 + i * 16 + lr][kf * 32 + kg * 8];
#pragma unroll
        for (int j = 0; j < 2; j++)
#pragma unroll
            for (int kf = 0; kf < 2; kf++)
                bb[j][kf] = *(const bf16x8*)&Bs[cur][wc * 32 + j * 16 + lr][kf * 32 + kg * 8];
#pragma unroll
        for (int i = 0; i < 2; i++)
#pragma unroll
            for (int j = 0; j < 2; j++) {
                acc[i][j] = __builtin_amdgcn_mfma_f32_16x16x32_bf16(a[i][0], bb[j][0], acc[i][j], 0, 0, 0);
                acc[i][j] = __builtin_amdgcn_mfma_f32_16x16x32_bf16(a[i][1], bb[j][1], acc[i][j], 0, 0, 0);
            }
        if (it < 7) {
            // write next tile into the other buffer (last read at iter it-1, barrier passed)
            *(uint4*)&As[cur ^ 1][srow][skq * 16]     = a01;
            *(uint4*)&As[cur ^ 1][srow][skq * 16 + 8] = a23;
            *(uint4*)&Bs[cur ^ 1][srow][skq * 16]     = b01;
            *(uint4*)&Bs[cur ^ 1][srow][skq * 16 + 8] = b23;
            __syncthreads();  // single barrier per iteration
        }
    }

    // C/D layout: col = lane&15, row = (lane>>4)*4 + reg
#pragma unroll
    for (int i = 0; i < 2; i++) {
#pragma unroll
        for (int r = 0; r < 4; r++) {
            int m = bm + wr * 32 + i * 16 + kg * 4 + r;
            if (m >= J.M) continue;
            const float* addrow = nullptr;
            if (J.Add) {
                int bb2 = m / J.addRows; int rr = m - bb2 * J.addRows;
                addrow = J.Add + bb2 * J.addBS + J.addOff + (long)rr * 512;
            }
            float* orow = J.Out + (long)m * 512;
#pragma unroll
            for (int j = 0; j < 2; j++) {
                int n = bn + wc * 32 + j * 16 + lr;
                float v = acc[i][j][r] * J.scale;
                if (J.bias) v += J.bias[n];
                if (J.relu) v = fmaxf(v, 0.f);
                if (addrow) v += addrow[n];
                orow[n] = v;
            }
        }
    }
}

// ---------------- attention 1 (wave-per-row): P[b,h,n,q] = softmax_n(q·k), transposed store ----
// 4 q-rows per block (one per wave); softmax entirely in-wave, no block barriers.
__global__ __launch_bounds__(256) void attn1_kernel(const float* __restrict__ qs,
                                                    const float* __restrict__ ks,
                                                    float* __restrict__ P) {
    int bid = blockIdx.x;          // 4*8*57
    int qt = bid % 57;
    int h = (bid / 57) % HEADS;
    int b = bid / (57 * HEADS);
    int wave = threadIdx.x >> 6, lane = threadIdx.x & 63;
    int qi = qt * 4 + wave;
    bool qok = (qi < QL);
    int qc = qok ? qi : QL - 1;
    __shared__ __align__(16) float qlds[4][64];
    qlds[wave][lane] = qs[((long)(b * QL + qc)) * DIM + h * 64 + lane];
    // wave-lockstep: same wave wrote all 64 floats before any lane reads them
    const float4* q4 = (const float4*)qlds[wave];
    const float* kbase = ks + ((long)(b * VS)) * DIM + h * 64;
    float sv[4];
#pragma unroll
    for (int k = 0; k < 4; k++) {
        int n = lane + 64 * k;
        float acc = -1e30f;
        if (n < VS) {
            const float4* kr4 = (const float4*)(kbase + (long)n * DIM);
            float a = 0.f;
#pragma unroll
            for (int i = 0; i < 16; i++) {
                float4 kv = kr4[i], qv = q4[i];
                a += qv.x * kv.x + qv.y * kv.y + qv.z * kv.z + qv.w * kv.w;
            }
            acc = a;
        }
        sv[k] = acc;
    }
    float m = fmaxf(fmaxf(sv[0], sv[1]), fmaxf(sv[2], sv[3]));
    m = waveMax(m);
    float e[4];
    float tot = 0.f;
#pragma unroll
    for (int k = 0; k < 4; k++) {
        int n = lane + 64 * k;
        e[k] = (n < VS) ? expf(sv[k] - m) : 0.f;
        tot += e[k];
    }
    tot = waveSum(tot);
    float inv = 1.f / tot;
    if (qok) {
        float* Pp = P + ((long)(b * HEADS + h)) * VS * QL + qi;
#pragma unroll
        for (int k = 0; k < 4; k++) {
            int n = lane + 64 * k;
            if (n < VS) Pp[(long)n * QL] = e[k] * inv;
        }
    }
}

// ---------------- fused: h = P*v -> dwconv1+bn1+relu -> dwconv2+bn2+relu -> mean over n ----
// v2 (proven 124us total), now split into 2 dispatches via `base` for rocprof visibility.
#define CSTEP(N, HAm,HAc,HAp, HBm,HBc,HBp, HCm,HCc,HCp, GAm,GAc,GAp, GBm,GBc,GBp, GCm,GCc,GCp) \
{                                                                                             \
    float pv = 0.f;                                                                           \
    if ((N) < VS) {                                                                           \
        float vn = vcol[(N)];                                                                 \
        if (qload) pv = Pp[(long)(N) * QL + q] * vn;                                          \
    }                                                                                         \
    HCc = pv;                                                                                 \
    HCm = __shfl_up(pv, 1, 64);                                                               \
    HCp = __shfl_down(pv, 1, 64);                                                             \
    float g = 0.f;                                                                            \
    if (gok && (N) >= 1 && (N) <= VS) {                                                       \
        float a1 = w1s[0]*HAm + w1s[1]*HAc + w1s[2]*HAp                                       \
                 + w1s[3]*HBm + w1s[4]*HBc + w1s[5]*HBp                                       \
                 + w1s[6]*HCm + w1s[7]*HCc + w1s[8]*HCp;                                      \
        g = fmaxf(a1 * s1 + b1v, 0.f);                                                        \
    }                                                                                         \
    GCc = g;                                                                                  \
    GCm = __shfl_up(g, 1, 64);                                                                \
    GCp = __shfl_down(g, 1, 64);                                                              \
    if ((N) >= 2) {                                                                           \
        float a2 = w2s[0]*GAm + w2s[1]*GAc + w2s[2]*GAp                                       \
                 + w2s[3]*GBm + w2s[4]*GBc + w2s[5]*GBp                                       \
                 + w2s[6]*GCm + w2s[7]*GCc + w2s[8]*GCp;                                      \
        csum += fmaxf(a2 * s2 + b2v, 0.f);                                                    \
    }                                                                                         \
}

__global__ __launch_bounds__(256) void conv_fuse_kernel(
    const float* __restrict__ P, const float* __restrict__ vs,
    const float* __restrict__ dw1, const float* __restrict__ dw2,
    const float* __restrict__ bn1g, const float* __restrict__ bn1b,
    const float* __restrict__ bn1m, const float* __restrict__ bn1v,
    const float* __restrict__ bn2g, const float* __restrict__ bn2b,
    const float* __restrict__ bn2m, const float* __restrict__ bn2v,
    float* __restrict__ m2, int base) {
    int bc = blockIdx.x + base;
    int c = bc & (DIM - 1);
    int b = bc >> 9;
    int h = c >> 6;
    int tid = threadIdx.x;
    int wave = tid >> 6, lane = tid & 63;
    int q = wave * 60 + lane - 2;
    bool qload = (q >= 0 && q < QL);
    bool gok = (lane >= 1 && lane <= 62 && q >= 0 && q < QL);
    bool outok = (lane >= 2 && lane <= 61 && q < QL);
    __shared__ float vcol[VS];
    if (tid < VS) vcol[tid] = vs[((long)(b * VS + tid)) * DIM + c];
    float w1s[9], w2s[9];
#pragma unroll
    for (int i = 0; i < 9; i++) { w1s[i] = dw1[c * 9 + i]; w2s[i] = dw2[c * 9 + i]; }
    float s1 = bn1g[c] * rsqrtf(bn1v[c] + EPS_BN);
    float b1v = bn1b[c] - bn1m[c] * s1;
    float s2 = bn2g[c] * rsqrtf(bn2v[c] + EPS_BN);
    float b2v = bn2b[c] - bn2m[c] * s2;
    const float* Pp = P + ((long)(b * HEADS + h)) * VS * QL;
    __syncthreads();
    float HAm = 0, HAc = 0, HAp = 0, HBm = 0, HBc = 0, HBp = 0, HCm = 0, HCc = 0, HCp = 0;
    float GAm = 0, GAc = 0, GAp = 0, GBm = 0, GBc = 0, GBp = 0, GCm = 0, GCc = 0, GCp = 0;
    float csum = 0.f;
    for (int nb = 0; nb < 198; nb += 3) {
        CSTEP(nb,     HAm,HAc,HAp, HBm,HBc,HBp, HCm,HCc,HCp, GAm,GAc,GAp, GBm,GBc,GBp, GCm,GCc,GCp)
        CSTEP(nb + 1, HBm,HBc,HBp, HCm,HCc,HCp, HAm,HAc,HAp, GBm,GBc,GBp, GCm,GCc,GCp, GAm,GAc,GAp)
        CSTEP(nb + 2, HCm,HCc,HCp, HAm,HAc,HAp, HBm,HBc,HBp, GCm,GCc,GCp, GAm,GAc,GAp, GBm,GBc,GBp)
    }
    if (outok) m2[((long)(b * QL + q)) * DIM + c] = csum * (1.f / (float)VS);
}

// ---------------- attention 2: O[b,n,:] = Qm[b,n,:] + softmax_q(Qm·Km/sqrt(512)) @ Vm ----
__global__ __launch_bounds__(256) void attn2_kernel(const float* __restrict__ Qm,
                                                    const float* __restrict__ Km,
                                                    const float* __restrict__ Vm,
                                                    float* __restrict__ O) {
    int bid = blockIdx.x;
    int n = bid % VS;
    int h = (bid / VS) % HEADS;
    int b = bid / (VS * HEADS);
    __shared__ __align__(16) float qrow[64];
    __shared__ float av[QL];
    __shared__ __align__(16) float4 red4[16][16];
    __shared__ float redm[4], reds[4];
    int tid = threadIdx.x;
    if (tid < 64) qrow[tid] = Qm[((long)(b * VS + n)) * DIM + h * 64 + tid];
    __syncthreads();
    float s = -1e30f;
    if (tid < QL) {
        const float4* kr4 = (const float4*)(Km + ((long)(b * QL + tid)) * DIM + h * 64);
        const float4* q4 = (const float4*)qrow;
        float acc = 0.f;
#pragma unroll
        for (int i = 0; i < 16; i++) {
            float4 kv = kr4[i], qv = q4[i];
            acc += qv.x * kv.x + qv.y * kv.y + qv.z * kv.z + qv.w * kv.w;
        }
        s = acc * 0.044194173824159216f; // 1/sqrt(512)
    }
    float wm = waveMax(s);
    if ((tid & 63) == 0) redm[tid >> 6] = wm;
    __syncthreads();
    float m = fmaxf(fmaxf(redm[0], redm[1]), fmaxf(redm[2], redm[3]));
    float e = (tid < QL) ? expf(s - m) : 0.f;
    float ws = waveSum(e);
    if ((tid & 63) == 0) reds[tid >> 6] = ws;
    __syncthreads();
    float tot = reds[0] + reds[1] + reds[2] + reds[3];
    if (tid < QL) av[tid] = e / tot;
    __syncthreads();
    int qp = tid >> 4, dq = tid & 15;
    float4 acc4 = make_float4(0, 0, 0, 0);
    for (int it = 0; it < 15; it++) {
        int qq = it * 16 + qp;
        if (qq < QL) {
            float a = av[qq];
            float4 v4 = *(const float4*)(Vm + ((long)(b * QL + qq)) * DIM + h * 64 + dq * 4);
            acc4.x += a * v4.x; acc4.y += a * v4.y; acc4.z += a * v4.z; acc4.w += a * v4.w;
        }
    }
    red4[qp][dq] = acc4;
    __syncthreads();
#pragma unroll
    for (int st = 8; st >= 1; st >>= 1) {
        if (qp < st) {
            float4 o = red4[qp + st][dq];
            acc4.x += o.x; acc4.y += o.y; acc4.z += o.z; acc4.w += o.w;
            red4[qp][dq] = acc4;
        }
        __syncthreads();
    }
    if (tid < 16) {
        float4 r = red4[0][tid];
        float4 qv = ((const float4*)qrow)[tid];
        float4 o = make_float4(qv.x + r.x, qv.y + r.y, qv.z + r.z, qv.w + r.w);
        *(float4*)(O + ((long)(b * VS + n)) * DIM + h * 64 + tid * 4) = o;
    }
}

static inline GJob mkjob(const float* A, int aRows, long aBS, long aOff,
                         const float* W, const float* bias,
                         const float* Add, int addRows, long addBS, long addOff,
                         float* Out, int M, float scale, int relu) {
    GJob j;
    j.A = A; j.W = W; j.bias = bias; j.Add = Add; j.Out = Out;
    j.aBS = aBS; j.aOff = aOff; j.addBS = addBS; j.addOff = addOff;
    j.aRows = aRows; j.addRows = addRows; j.M = M; j.relu = relu;
    j.scale = scale; j.pad0 = j.pad1 = j.pad2 = 0;
    return j;
}

extern "C" void kernel_launch(void* const* d_in, const int* in_sizes, int n_in,
                              void* d_out, int out_size, void* d_ws, size_t ws_size,
                              hipStream_t stream) {
    const float* x     = (const float*)d_in[0];
    const float* Wq    = (const float*)d_in[1];
    const float* Wk    = (const float*)d_in[2];
    const float* Wv    = (const float*)d_in[3];
    const float* Wproj = (const float*)d_in[4];
    const float* bproj = (const float*)d_in[5];
    const float* dw1   = (const float*)d_in[6];
    const float* dw2   = (const float*)d_in[7];
    const float* pw    = (const float*)d_in[8];
    const float* bn1g  = (const float*)d_in[9];
    const float* bn1b  = (const float*)d_in[10];
    const float* bn1m  = (const float*)d_in[11];
    const float* bn1v  = (const float*)d_in[12];
    const float* bn2g  = (const float*)d_in[13];
    const float* bn2b  = (const float*)d_in[14];
    const float* bn2m  = (const float*)d_in[15];
    const float* bn2v  = (const float*)d_in[16];
    const float* mWq   = (const float*)d_in[17];
    const float* mbq   = (const float*)d_in[18];
    const float* mWk   = (const float*)d_in[19];
    const float* mbk   = (const float*)d_in[20];
    const float* mWv   = (const float*)d_in[21];
    const float* mbv   = (const float*)d_in[22];
    const float* mWo   = (const float*)d_in[23];
    const float* mbo   = (const float*)d_in[24];

    float* ws = (float*)d_ws;
    // Overlay (floats):
    //   qs @ 0 (460800) -> m2 -> Km
    //   ks @ 460800 (401408) -> O
    //   vsb @ 862208 (401408) -> O2
    //   P @ 1263616 (1411200) -> [kc @ +0 | Qm @ +460800 | Vm @ +862208]
    float* qs = ws;
    float* ks = ws + 460800;
    float* vsb = ws + 862208;
    float* P  = ws + 1263616;
    float* m2 = ws;
    float* kc = ws + 1263616;
    float* Qm = ws + 1263616 + 460800;
    float* Vm = ws + 1263616 + 460800 + 401408;
    float* Km = ws;
    float* O  = ws + 460800;
    float* O2 = ws + 862208;

    const long xBS = 421L * DIM;
    const long clsOff = 196L * DIM;

    dim3 blk(256);

    // L1: q,k,v projections fused (360 blocks)
    {
        GJobs js;
        js.j[0] = mkjob(x, QL, xBS, clsOff, Wq, nullptr, nullptr, 1, 0, 0, qs, 900, 0.125f, 0);
        js.j[1] = mkjob(x, VS, xBS, 0, Wk, nullptr, nullptr, 1, 0, 0, ks, 784, 1.f, 0);
        js.j[2] = mkjob(x, VS, xBS, 0, Wv, nullptr, nullptr, 1, 0, 0, vsb, 784, 1.f, 0);
        js.j[3] = js.j[0];
        gemm_multi<0><<<dim3(8, 15, 3), blk, 0, stream>>>(js);
    }
    attn1_kernel<<<BATCH * HEADS * 57, blk, 0, stream>>>(qs, ks, P);
    // conv in two independent halves (visibility: exposes other kernels in rocprof top-5)
    conv_fuse_kernel<<<1024, blk, 0, stream>>>(P, vsb, dw1, dw2,
                                               bn1g, bn1b, bn1m, bn1v,
                                               bn2g, bn2b, bn2m, bn2v, m2, 0);
    conv_fuse_kernel<<<1024, blk, 0, stream>>>(P, vsb, dw1, dw2,
                                               bn1g, bn1b, bn1m, bn1v,
                                               bn2g, bn2b, bn2m, bn2v, m2, 1024);
    // L2: kc = cls_cat + m2 @ pw^T  AND  Qm = x_sem @ mWq^T + mbq   (P dead now)
    {
        GJobs js;
        js.j[0] = mkjob(m2, 900, 0, 0, pw, nullptr, x, QL, xBS, clsOff, kc, 900, 1.f, 0);
        js.j[1] = mkjob(x, VS, xBS, 0, mWq, mbq, nullptr, 1, 0, 0, Qm, 784, 1.f, 0);
        js.j[2] = js.j[3] = js.j[0];
        gemm_multi<1><<<dim3(8, 15, 2), blk, 0, stream>>>(js);
    }
    // L3: Km, Vm off kc
    {
        GJobs js;
        js.j[0] = mkjob(kc, 900, 0, 0, mWk, mbk, nullptr, 1, 0, 0, Km, 900, 1.f, 0);
        js.j[1] = mkjob(kc, 900, 0, 0, mWv, mbv, nullptr, 1, 0, 0, Vm, 900, 1.f, 0);
        js.j[2] = js.j[3] = js.j[0];
        gemm_multi<2><<<dim3(8, 15, 2), blk, 0, stream>>>(js);
    }
    attn2_kernel<<<BATCH * HEADS * VS, blk, 0, stream>>>(Qm, Km, Vm, O);
    // L4: O2 = O + relu(O @ mWo^T + mbo)
    {
        GJobs js;
        js.j[0] = mkjob(O, 784, 0, 0, mWo, mbo, O, 784, 0, 0, O2, 784, 1.f, 1);
        js.j[1] = js.j[2] = js.j[3] = js.j[0];
        gemm_multi<3><<<dim3(8, 13, 1), blk, 0, stream>>>(js);
    }
    // L5: out = O2 @ Wproj^T + bproj
    {
        GJobs js;
        js.j[0] = mkjob(O2, 784, 0, 0, Wproj, bproj, nullptr, 1, 0, 0, (float*)d_out, 784, 1.f, 0);
        js.j[1] = js.j[2] = js.j[3] = js.j[0];
        gemm_multi<4><<<dim3(8, 13, 1), blk, 0, stream>>>(js);
    }
}

// Round 10
// 255.631 us; speedup vs baseline: 1.4256x; 1.4256x over previous
//
#include <hip/hip_runtime.h>
#include <math.h>

#define DIM 512
#define HEADS 8
#define QL 225
#define VS 196
#define BATCH 4
#define EPS_BN 1e-5f

typedef __attribute__((ext_vector_type(8))) short bf16x8;
typedef __attribute__((ext_vector_type(4))) float f32x4;

// ---------------- wave (64-lane) reductions ----------------
__device__ __forceinline__ float waveMax(float v) {
#pragma unroll
    for (int o = 32; o; o >>= 1) v = fmaxf(v, __shfl_xor(v, o, 64));
    return v;
}
__device__ __forceinline__ float waveSum(float v) {
#pragma unroll
    for (int o = 32; o; o >>= 1) v += __shfl_xor(v, o, 64);
    return v;
}

// ---------------- fp32 -> bf16 pack helpers ----------------
__device__ __forceinline__ unsigned cvt_pk_bf16(float lo, float hi) {
    unsigned r;
    asm("v_cvt_pk_bf16_f32 %0, %1, %2" : "=v"(r) : "v"(lo), "v"(hi));
    return r;
}
__device__ __forceinline__ uint4 ld_cvt8(const float* p) {
    float4 x = *(const float4*)p;
    float4 y = *(const float4*)(p + 4);
    uint4 r;
    r.x = cvt_pk_bf16(x.x, x.y);
    r.y = cvt_pk_bf16(x.z, x.w);
    r.z = cvt_pk_bf16(y.x, y.y);
    r.w = cvt_pk_bf16(y.z, y.w);
    return r;
}

// ---------------- multi-job bf16-MFMA GEMM (N=K=512): Out = scale*A@W^T (+bias)(relu)(+Add) ----
// (R8-proven version: 64x64 tile, BK=64, preloaded global loads)
struct GJob {
    const float* A; const float* W; const float* bias; const float* Add; float* Out;
    long aBS, aOff, addBS, addOff;
    int aRows, addRows, M, relu;
    float scale; int pad0, pad1, pad2;
};
struct GJobs { GJob j[4]; };

template<int LAYER>
__global__ __launch_bounds__(256) void gemm_multi(GJobs jobs) {
    const GJob J = jobs.j[blockIdx.z];
    const int bm = blockIdx.y * 64, bn = blockIdx.x * 64;
    if (bm >= J.M) return;
    __shared__ __align__(16) ushort As[64][72];
    __shared__ __align__(16) ushort Bs[64][72];
    const int tid = threadIdx.x;
    const int srow = tid >> 2, skq = tid & 3;
    const float* ap = nullptr;
    {
        int m = bm + srow;
        if (m < J.M) { int bb = m / J.aRows; int r = m - bb * J.aRows;
                       ap = J.A + bb * J.aBS + J.aOff + (long)r * 512 + skq * 16; }
    }
    const float* bp = J.W + (long)(bn + srow) * 512 + skq * 16;

    const int lane = tid & 63, wid = tid >> 6;
    const int wr = wid >> 1, wc = wid & 1;
    const int lr = lane & 15, kg = lane >> 4;

    f32x4 acc[2][2] = {};

    uint4 a01 = {0u,0u,0u,0u}, a23 = {0u,0u,0u,0u};
    if (ap) { a01 = ld_cvt8(ap); a23 = ld_cvt8(ap + 8); }
    uint4 b01 = ld_cvt8(bp), b23 = ld_cvt8(bp + 8);

    for (int kt = 0; kt < 512; kt += 64) {
        __syncthreads();
        *(uint4*)&As[srow][skq * 16]     = a01;
        *(uint4*)&As[srow][skq * 16 + 8] = a23;
        *(uint4*)&Bs[srow][skq * 16]     = b01;
        *(uint4*)&Bs[srow][skq * 16 + 8] = b23;
        __syncthreads();
        if (kt + 64 < 512) {
            if (ap) { a01 = ld_cvt8(ap + kt + 64); a23 = ld_cvt8(ap + kt + 72); }
            b01 = ld_cvt8(bp + kt + 64); b23 = ld_cvt8(bp + kt + 72);
        }
        bf16x8 a[2][2], bb[2][2];
#pragma unroll
        for (int i = 0; i < 2; i++)
#pragma unroll
            for (int kf = 0; kf < 2; kf++)
                a[i][kf] = *(const bf16x8*)&As[wr * 32 + i * 16 + lr][kf * 32 + kg * 8];
#pragma unroll
        for (int j = 0; j < 2; j++)
#pragma unroll
            for (int kf = 0; kf < 2; kf++)
                bb[j][kf] = *(const bf16x8*)&Bs[wc * 32 + j * 16 + lr][kf * 32 + kg * 8];
#pragma unroll
        for (int i = 0; i < 2; i++)
#pragma unroll
            for (int j = 0; j < 2; j++) {
                acc[i][j] = __builtin_amdgcn_mfma_f32_16x16x32_bf16(a[i][0], bb[j][0], acc[i][j], 0, 0, 0);
                acc[i][j] = __builtin_amdgcn_mfma_f32_16x16x32_bf16(a[i][1], bb[j][1], acc[i][j], 0, 0, 0);
            }
    }

#pragma unroll
    for (int i = 0; i < 2; i++) {
#pragma unroll
        for (int r = 0; r < 4; r++) {
            int m = bm + wr * 32 + i * 16 + kg * 4 + r;
            if (m >= J.M) continue;
            const float* addrow = nullptr;
            if (J.Add) {
                int bb2 = m / J.addRows; int rr = m - bb2 * J.addRows;
                addrow = J.Add + bb2 * J.addBS + J.addOff + (long)rr * 512;
            }
            float* orow = J.Out + (long)m * 512;
#pragma unroll
            for (int j = 0; j < 2; j++) {
                int n = bn + wc * 32 + j * 16 + lr;
                float v = acc[i][j][r] * J.scale;
                if (J.bias) v += J.bias[n];
                if (J.relu) v = fmaxf(v, 0.f);
                if (addrow) v += addrow[n];
                orow[n] = v;
            }
        }
    }
}

// ---------------- attention 1 (R8-proven): P[b,h,n,q] = softmax_n( q·k ), transposed store ----
__global__ __launch_bounds__(256) void attn1_kernel(const float* __restrict__ qs,
                                                    const float* __restrict__ ks,
                                                    float* __restrict__ P) {
    int bid = blockIdx.x;
    int qi = bid % QL;
    int h = (bid / QL) % HEADS;
    int b = bid / (QL * HEADS);
    __shared__ __align__(16) float qrow[64];
    __shared__ float redm[4], reds[4];
    int tid = threadIdx.x;
    if (tid < 64) qrow[tid] = qs[((long)(b * QL + qi)) * DIM + h * 64 + tid];
    __syncthreads();
    float s = -1e30f;
    if (tid < VS) {
        const float4* kr4 = (const float4*)(ks + ((long)(b * VS + tid)) * DIM + h * 64);
        const float4* q4 = (const float4*)qrow;
        float acc = 0.f;
#pragma unroll
        for (int i = 0; i < 16; i++) {
            float4 kv = kr4[i], qv = q4[i];
            acc += qv.x * kv.x + qv.y * kv.y + qv.z * kv.z + qv.w * kv.w;
        }
        s = acc;
    }
    float wm = waveMax(s);
    if ((tid & 63) == 0) redm[tid >> 6] = wm;
    __syncthreads();
    float m = fmaxf(fmaxf(redm[0], redm[1]), fmaxf(redm[2], redm[3]));
    float e = (tid < VS) ? expf(s - m) : 0.f;
    float ws = waveSum(e);
    if ((tid & 63) == 0) reds[tid >> 6] = ws;
    __syncthreads();
    float tot = reds[0] + reds[1] + reds[2] + reds[3];
    if (tid < VS) P[(((long)(b * HEADS + h)) * VS + tid) * QL + qi] = e / tot;
}

// ---------------- fused conv (R8-proven v2, single 2048-block dispatch) ----------------
#define CSTEP(N, HAm,HAc,HAp, HBm,HBc,HBp, HCm,HCc,HCp, GAm,GAc,GAp, GBm,GBc,GBp, GCm,GCc,GCp) \
{                                                                                             \
    float pv = 0.f;                                                                           \
    if ((N) < VS) {                                                                           \
        float vn = vcol[(N)];                                                                 \
        if (qload) pv = Pp[(long)(N) * QL + q] * vn;                                          \
    }                                                                                         \
    HCc = pv;                                                                                 \
    HCm = __shfl_up(pv, 1, 64);                                                               \
    HCp = __shfl_down(pv, 1, 64);                                                             \
    float g = 0.f;                                                                            \
    if (gok && (N) >= 1 && (N) <= VS) {                                                       \
        float a1 = w1s[0]*HAm + w1s[1]*HAc + w1s[2]*HAp                                       \
                 + w1s[3]*HBm + w1s[4]*HBc + w1s[5]*HBp                                       \
                 + w1s[6]*HCm + w1s[7]*HCc + w1s[8]*HCp;                                      \
        g = fmaxf(a1 * s1 + b1v, 0.f);                                                        \
    }                                                                                         \
    GCc = g;                                                                                  \
    GCm = __shfl_up(g, 1, 64);                                                                \
    GCp = __shfl_down(g, 1, 64);                                                              \
    if ((N) >= 2) {                                                                           \
        float a2 = w2s[0]*GAm + w2s[1]*GAc + w2s[2]*GAp                                       \
                 + w2s[3]*GBm + w2s[4]*GBc + w2s[5]*GBp                                       \
                 + w2s[6]*GCm + w2s[7]*GCc + w2s[8]*GCp;                                      \
        csum += fmaxf(a2 * s2 + b2v, 0.f);                                                    \
    }                                                                                         \
}

__global__ __launch_bounds__(256) void conv_fuse_kernel(
    const float* __restrict__ P, const float* __restrict__ vs,
    const float* __restrict__ dw1, const float* __restrict__ dw2,
    const float* __restrict__ bn1g, const float* __restrict__ bn1b,
    const float* __restrict__ bn1m, const float* __restrict__ bn1v,
    const float* __restrict__ bn2g, const float* __restrict__ bn2b,
    const float* __restrict__ bn2m, const float* __restrict__ bn2v,
    float* __restrict__ m2) {
    int bc = blockIdx.x;
    int c = bc & (DIM - 1);
    int b = bc >> 9;
    int h = c >> 6;
    int tid = threadIdx.x;
    int wave = tid >> 6, lane = tid & 63;
    int q = wave * 60 + lane - 2;
    bool qload = (q >= 0 && q < QL);
    bool gok = (lane >= 1 && lane <= 62 && q >= 0 && q < QL);
    bool outok = (lane >= 2 && lane <= 61 && q < QL);
    __shared__ float vcol[VS];
    if (tid < VS) vcol[tid] = vs[((long)(b * VS + tid)) * DIM + c];
    float w1s[9], w2s[9];
#pragma unroll
    for (int i = 0; i < 9; i++) { w1s[i] = dw1[c * 9 + i]; w2s[i] = dw2[c * 9 + i]; }
    float s1 = bn1g[c] * rsqrtf(bn1v[c] + EPS_BN);
    float b1v = bn1b[c] - bn1m[c] * s1;
    float s2 = bn2g[c] * rsqrtf(bn2v[c] + EPS_BN);
    float b2v = bn2b[c] - bn2m[c] * s2;
    const float* Pp = P + ((long)(b * HEADS + h)) * VS * QL;
    __syncthreads();
    float HAm = 0, HAc = 0, HAp = 0, HBm = 0, HBc = 0, HBp = 0, HCm = 0, HCc = 0, HCp = 0;
    float GAm = 0, GAc = 0, GAp = 0, GBm = 0, GBc = 0, GBp = 0, GCm = 0, GCc = 0, GCp = 0;
    float csum = 0.f;
    for (int nb = 0; nb < 198; nb += 3) {
        CSTEP(nb,     HAm,HAc,HAp, HBm,HBc,HBp, HCm,HCc,HCp, GAm,GAc,GAp, GBm,GBc,GBp, GCm,GCc,GCp)
        CSTEP(nb + 1, HBm,HBc,HBp, HCm,HCc,HCp, HAm,HAc,HAp, GBm,GBc,GBp, GCm,GCc,GCp, GAm,GAc,GAp)
        CSTEP(nb + 2, HCm,HCc,HCp, HAm,HAc,HAp, HBm,HBc,HBp, GCm,GCc,GCp, GAm,GAc,GAp, GBm,GBc,GBp)
    }
    if (outok) m2[((long)(b * QL + q)) * DIM + c] = csum * (1.f / (float)VS);
}

// ---------------- attention 2 via MFMA: O = Qm + softmax_q(Qm Km^T / sqrt(512)) Vm ----
// Block = (b, h, 64-row n-slice); 4 waves, wave owns a 16-row tile.
// Phase A: scores (bf16 MFMA, 15 q-col-tiles x K=64). In-register row softmax.
// Phase B: P (bf16, LDS) @ V^T (bf16, LDS) over padded K=256.
__global__ __launch_bounds__(256) void attn2_mfma(const float* __restrict__ Qm,
                                                  const float* __restrict__ Km,
                                                  const float* __restrict__ Vm,
                                                  float* __restrict__ O) {
    int bid = blockIdx.x;          // 128 = b(4) x h(8) x nq(4)
    int nq = bid & 3;
    int h = (bid >> 2) & 7;
    int b = bid >> 5;
    int n0 = nq * 64;
    int tid = threadIdx.x;
    int wave = tid >> 6, lane = tid & 63;
    int lr = lane & 15, kg = lane >> 4;

    // LDS union: [VT 33792][ Qb 9216 | Kb 34560  ->  Pl 33792 ]
    __shared__ __align__(16) char smem[77568];
    ushort (*VT)[264] = (ushort(*)[264])smem;            // [64][264]  VT[d][q]
    ushort (*Qb)[72]  = (ushort(*)[72])(smem + 33792);   // [64][72]
    ushort (*Kb)[72]  = (ushort(*)[72])(smem + 43008);   // [240][72]
    ushort (*Pl)[264] = (ushort(*)[264])(smem + 33792);  // [64][264] aliases Qb/Kb

    const long qmBase = ((long)(b * VS)) * DIM + h * 64;
    const long kmBase = ((long)(b * QL)) * DIM + h * 64;

    {   // stage Qb (rows clamped to valid n)
        int r = tid >> 2, c0 = (tid & 3) * 16;
        int n = min(n0 + r, VS - 1);
        const float* src = Qm + qmBase + (long)n * DIM + c0;
        *(uint4*)&Qb[r][c0]     = ld_cvt8(src);
        *(uint4*)&Qb[r][c0 + 8] = ld_cvt8(src + 8);
    }
    {   // stage Kb rows 0..239 (zeros for q >= 225)
        int c0 = (tid & 3) * 16;
#pragma unroll
        for (int i = 0; i < 4; i++) {
            int r = (tid >> 2) + 64 * i;
            if (r < 240) {
                uint4 lo = {0u,0u,0u,0u}, hi = {0u,0u,0u,0u};
                if (r < QL) {
                    const float* src = Km + kmBase + (long)r * DIM + c0;
                    lo = ld_cvt8(src); hi = ld_cvt8(src + 8);
                }
                *(uint4*)&Kb[r][c0]     = lo;
                *(uint4*)&Kb[r][c0 + 8] = hi;
            }
        }
    }
    {   // stage VT[d][q] (transposed, zeros for q >= 225; also q in [240,256))
        int c0 = (tid & 3) * 16;
#pragma unroll
        for (int i = 0; i < 4; i++) {
            int qq = (tid >> 2) + 64 * i;
            if (qq < 240) {
                ushort u[16];
                if (qq < QL) {
                    const float* src = Vm + kmBase + (long)qq * DIM + c0;
                    *(uint4*)&u[0] = ld_cvt8(src);
                    *(uint4*)&u[8] = ld_cvt8(src + 8);
                } else {
#pragma unroll
                    for (int j = 0; j < 16; j++) u[j] = 0;
                }
#pragma unroll
                for (int j = 0; j < 16; j++) VT[c0 + j][qq] = u[j];
            }
        }
        int d = tid >> 2, qz = 240 + (tid & 3) * 4;
#pragma unroll
        for (int j = 0; j < 4; j++) VT[d][qz + j] = 0;
    }
    __syncthreads();

    // ---- phase A: scores for this wave's 16-row tile ----
    bf16x8 a0 = *(const bf16x8*)&Qb[wave * 16 + lr][kg * 8];
    bf16x8 a1 = *(const bf16x8*)&Qb[wave * 16 + lr][32 + kg * 8];
    f32x4 sc[15];
#pragma unroll
    for (int ct = 0; ct < 15; ct++) {
        bf16x8 b0 = *(const bf16x8*)&Kb[ct * 16 + lr][kg * 8];
        bf16x8 b1 = *(const bf16x8*)&Kb[ct * 16 + lr][32 + kg * 8];
        f32x4 z = {0.f, 0.f, 0.f, 0.f};
        z = __builtin_amdgcn_mfma_f32_16x16x32_bf16(a0, b0, z, 0, 0, 0);
        z = __builtin_amdgcn_mfma_f32_16x16x32_bf16(a1, b1, z, 0, 0, 0);
        sc[ct] = z;
    }
    __syncthreads();   // Qb/Kb reads complete; Pl region may be overwritten

    // ---- in-register row softmax (C/D: col=lane&15, row=(lane>>4)*4+r) ----
    const float scl = 0.044194173824159216f; // 1/sqrt(512)
    float pinv[4];
#pragma unroll
    for (int r = 0; r < 4; r++) {
        float m = -1e30f;
#pragma unroll
        for (int ct = 0; ct < 15; ct++) {
            float v = sc[ct][r] * scl;
            if (ct * 16 + lr >= QL) v = -1e30f;    // q-pad mask (only ct=14)
            sc[ct][r] = v;
            m = fmaxf(m, v);
        }
#pragma unroll
        for (int o = 1; o < 16; o <<= 1) m = fmaxf(m, __shfl_xor(m, o, 64));
        float s = 0.f;
#pragma unroll
        for (int ct = 0; ct < 15; ct++) {
            float e = expf(sc[ct][r] - m);
            sc[ct][r] = e;
            s += e;
        }
#pragma unroll
        for (int o = 1; o < 16; o <<= 1) s += __shfl_xor(s, o, 64);
        pinv[r] = 1.f / s;
    }
    // write normalized P (bf16) into Pl; zero K-pad cols [240,256)
#pragma unroll
    for (int r = 0; r < 4; r++) {
        int row = wave * 16 + (lane >> 4) * 4 + r;
#pragma unroll
        for (int ct = 0; ct < 15; ct++) {
            float p = sc[ct][r] * pinv[r];
            Pl[row][ct * 16 + lr] = (ushort)(cvt_pk_bf16(p, p) & 0xffffu);
        }
        Pl[row][240 + lr] = 0;
    }
    __syncthreads();

    // ---- phase B: PV over padded K=256 ----
    bf16x8 pa[8];
#pragma unroll
    for (int ks = 0; ks < 8; ks++)
        pa[ks] = *(const bf16x8*)&Pl[wave * 16 + lr][ks * 32 + kg * 8];
    f32x4 ov[4] = {};
#pragma unroll
    for (int dt = 0; dt < 4; dt++)
#pragma unroll
        for (int ks = 0; ks < 8; ks++) {
            bf16x8 vb = *(const bf16x8*)&VT[dt * 16 + lr][ks * 32 + kg * 8];
            ov[dt] = __builtin_amdgcn_mfma_f32_16x16x32_bf16(pa[ks], vb, ov[dt], 0, 0, 0);
        }

    // ---- epilogue: O = Qm + PV ----
#pragma unroll
    for (int dt = 0; dt < 4; dt++)
#pragma unroll
        for (int r = 0; r < 4; r++) {
            int n = n0 + wave * 16 + (lane >> 4) * 4 + r;
            if (n < VS) {
                long addr = qmBase + (long)n * DIM + dt * 16 + lr;
                O[addr] = Qm[addr] + ov[dt][r];
            }
        }
}

static inline GJob mkjob(const float* A, int aRows, long aBS, long aOff,
                         const float* W, const float* bias,
                         const float* Add, int addRows, long addBS, long addOff,
                         float* Out, int M, float scale, int relu) {
    GJob j;
    j.A = A; j.W = W; j.bias = bias; j.Add = Add; j.Out = Out;
    j.aBS = aBS; j.aOff = aOff; j.addBS = addBS; j.addOff = addOff;
    j.aRows = aRows; j.addRows = addRows; j.M = M; j.relu = relu;
    j.scale = scale; j.pad0 = j.pad1 = j.pad2 = 0;
    return j;
}

extern "C" void kernel_launch(void* const* d_in, const int* in_sizes, int n_in,
                              void* d_out, int out_size, void* d_ws, size_t ws_size,
                              hipStream_t stream) {
    const float* x     = (const float*)d_in[0];
    const float* Wq    = (const float*)d_in[1];
    const float* Wk    = (const float*)d_in[2];
    const float* Wv    = (const float*)d_in[3];
    const float* Wproj = (const float*)d_in[4];
    const float* bproj = (const float*)d_in[5];
    const float* dw1   = (const float*)d_in[6];
    const float* dw2   = (const float*)d_in[7];
    const float* pw    = (const float*)d_in[8];
    const float* bn1g  = (const float*)d_in[9];
    const float* bn1b  = (const float*)d_in[10];
    const float* bn1m  = (const float*)d_in[11];
    const float* bn1v  = (const float*)d_in[12];
    const float* bn2g  = (const float*)d_in[13];
    const float* bn2b  = (const float*)d_in[14];
    const float* bn2m  = (const float*)d_in[15];
    const float* bn2v  = (const float*)d_in[16];
    const float* mWq   = (const float*)d_in[17];
    const float* mbq   = (const float*)d_in[18];
    const float* mWk   = (const float*)d_in[19];
    const float* mbk   = (const float*)d_in[20];
    const float* mWv   = (const float*)d_in[21];
    const float* mbv   = (const float*)d_in[22];
    const float* mWo   = (const float*)d_in[23];
    const float* mbo   = (const float*)d_in[24];

    float* ws = (float*)d_ws;
    // Overlay (floats):
    //   qs @ 0 (460800) -> m2 -> Km
    //   ks @ 460800 (401408) -> O
    //   vsb @ 862208 (401408) -> O2
    //   P @ 1263616 (1411200) -> [kc @ +0 | Qm @ +460800 | Vm @ +862208]
    float* qs = ws;
    float* ks = ws + 460800;
    float* vsb = ws + 862208;
    float* P  = ws + 1263616;
    float* m2 = ws;
    float* kc = ws + 1263616;
    float* Qm = ws + 1263616 + 460800;
    float* Vm = ws + 1263616 + 460800 + 401408;
    float* Km = ws;
    float* O  = ws + 460800;
    float* O2 = ws + 862208;

    const long xBS = 421L * DIM;
    const long clsOff = 196L * DIM;

    dim3 blk(256);

    // L1: q,k,v projections fused (360 blocks)
    {
        GJobs js;
        js.j[0] = mkjob(x, QL, xBS, clsOff, Wq, nullptr, nullptr, 1, 0, 0, qs, 900, 0.125f, 0);
        js.j[1] = mkjob(x, VS, xBS, 0, Wk, nullptr, nullptr, 1, 0, 0, ks, 784, 1.f, 0);
        js.j[2] = mkjob(x, VS, xBS, 0, Wv, nullptr, nullptr, 1, 0, 0, vsb, 784, 1.f, 0);
        js.j[3] = js.j[0];
        gemm_multi<0><<<dim3(8, 15, 3), blk, 0, stream>>>(js);
    }
    attn1_kernel<<<BATCH * HEADS * QL, blk, 0, stream>>>(qs, ks, P);
    conv_fuse_kernel<<<BATCH * DIM, blk, 0, stream>>>(P, vsb, dw1, dw2,
                                                      bn1g, bn1b, bn1m, bn1v,
                                                      bn2g, bn2b, bn2m, bn2v, m2);
    // L2: kc = cls_cat + m2 @ pw^T  AND  Qm = x_sem @ mWq^T + mbq   (P dead now)
    {
        GJobs js;
        js.j[0] = mkjob(m2, 900, 0, 0, pw, nullptr, x, QL, xBS, clsOff, kc, 900, 1.f, 0);
        js.j[1] = mkjob(x, VS, xBS, 0, mWq, mbq, nullptr, 1, 0, 0, Qm, 784, 1.f, 0);
        js.j[2] = js.j[3] = js.j[0];
        gemm_multi<1><<<dim3(8, 15, 2), blk, 0, stream>>>(js);
    }
    // L3: Km, Vm off kc
    {
        GJobs js;
        js.j[0] = mkjob(kc, 900, 0, 0, mWk, mbk, nullptr, 1, 0, 0, Km, 900, 1.f, 0);
        js.j[1] = mkjob(kc, 900, 0, 0, mWv, mbv, nullptr, 1, 0, 0, Vm, 900, 1.f, 0);
        js.j[2] = js.j[3] = js.j[0];
        gemm_multi<2><<<dim3(8, 15, 2), blk, 0, stream>>>(js);
    }
    attn2_mfma<<<BATCH * HEADS * 4, blk, 0, stream>>>(Qm, Km, Vm, O);
    // L4: O2 = O + relu(O @ mWo^T + mbo)
    {
        GJobs js;
        js.j[0] = mkjob(O, 784, 0, 0, mWo, mbo, O, 784, 0, 0, O2, 784, 1.f, 1);
        js.j[1] = js.j[2] = js.j[3] = js.j[0];
        gemm_multi<3><<<dim3(8, 13, 1), blk, 0, stream>>>(js);
    }
    // L5: out = O2 @ Wproj^T + bproj
    {
        GJobs js;
        js.j[0] = mkjob(O2, 784, 0, 0, Wproj, bproj, nullptr, 1, 0, 0, (float*)d_out, 784, 1.f, 0);
        js.j[1] = js.j[2] = js.j[3] = js.j[0];
        gemm_multi<4><<<dim3(8, 13, 1), blk, 0, stream>>>(js);
    }
}

// Round 11
// 239.145 us; speedup vs baseline: 1.5239x; 1.0689x over previous
//
#include <hip/hip_runtime.h>
#include <math.h>

#define DIM 512
#define HEADS 8
#define QL 225
#define VS 196
#define BATCH 4
#define EPS_BN 1e-5f

typedef __attribute__((ext_vector_type(8))) short bf16x8;
typedef __attribute__((ext_vector_type(4))) float f32x4;
typedef __attribute__((ext_vector_type(2))) float f32x2;

// ---------------- wave (64-lane) reductions ----------------
__device__ __forceinline__ float waveMax(float v) {
#pragma unroll
    for (int o = 32; o; o >>= 1) v = fmaxf(v, __shfl_xor(v, o, 64));
    return v;
}
__device__ __forceinline__ float waveSum(float v) {
#pragma unroll
    for (int o = 32; o; o >>= 1) v += __shfl_xor(v, o, 64);
    return v;
}

// ---------------- packed fp32 FMA (CDNA dual-issue FP32) ----------------
__device__ __forceinline__ f32x2 pk_fma(f32x2 a, f32x2 b, f32x2 c) {
    f32x2 d;
    asm("v_pk_fma_f32 %0, %1, %2, %3" : "=v"(d) : "v"(a), "v"(b), "v"(c));
    return d;
}

// ---------------- fp32 -> bf16 pack helpers ----------------
__device__ __forceinline__ unsigned cvt_pk_bf16(float lo, float hi) {
    unsigned r;
    asm("v_cvt_pk_bf16_f32 %0, %1, %2" : "=v"(r) : "v"(lo), "v"(hi));
    return r;
}
__device__ __forceinline__ uint4 ld_cvt8(const float* p) {
    float4 x = *(const float4*)p;
    float4 y = *(const float4*)(p + 4);
    uint4 r;
    r.x = cvt_pk_bf16(x.x, x.y);
    r.y = cvt_pk_bf16(x.z, x.w);
    r.z = cvt_pk_bf16(y.x, y.y);
    r.w = cvt_pk_bf16(y.z, y.w);
    return r;
}

// ---------------- multi-job bf16-MFMA GEMM (N=K=512): Out = scale*A@W^T (+bias)(relu)(+Add) ----
struct GJob {
    const float* A; const float* W; const float* bias; const float* Add; float* Out;
    long aBS, aOff, addBS, addOff;
    int aRows, addRows, M, relu;
    float scale; int pad0, pad1, pad2;
};
struct GJobs { GJob j[4]; };

template<int LAYER>
__global__ __launch_bounds__(256) void gemm_multi(GJobs jobs) {
    const GJob J = jobs.j[blockIdx.z];
    const int bm = blockIdx.y * 64, bn = blockIdx.x * 64;
    if (bm >= J.M) return;
    __shared__ __align__(16) ushort As[64][72];
    __shared__ __align__(16) ushort Bs[64][72];
    const int tid = threadIdx.x;
    const int srow = tid >> 2, skq = tid & 3;
    const float* ap = nullptr;
    {
        int m = bm + srow;
        if (m < J.M) { int bb = m / J.aRows; int r = m - bb * J.aRows;
                       ap = J.A + bb * J.aBS + J.aOff + (long)r * 512 + skq * 16; }
    }
    const float* bp = J.W + (long)(bn + srow) * 512 + skq * 16;

    const int lane = tid & 63, wid = tid >> 6;
    const int wr = wid >> 1, wc = wid & 1;
    const int lr = lane & 15, kg = lane >> 4;

    f32x4 acc[2][2] = {};

    uint4 a01 = {0u,0u,0u,0u}, a23 = {0u,0u,0u,0u};
    if (ap) { a01 = ld_cvt8(ap); a23 = ld_cvt8(ap + 8); }
    uint4 b01 = ld_cvt8(bp), b23 = ld_cvt8(bp + 8);

    for (int kt = 0; kt < 512; kt += 64) {
        __syncthreads();
        *(uint4*)&As[srow][skq * 16]     = a01;
        *(uint4*)&As[srow][skq * 16 + 8] = a23;
        *(uint4*)&Bs[srow][skq * 16]     = b01;
        *(uint4*)&Bs[srow][skq * 16 + 8] = b23;
        __syncthreads();
        if (kt + 64 < 512) {
            if (ap) { a01 = ld_cvt8(ap + kt + 64); a23 = ld_cvt8(ap + kt + 72); }
            b01 = ld_cvt8(bp + kt + 64); b23 = ld_cvt8(bp + kt + 72);
        }
        bf16x8 a[2][2], bb[2][2];
#pragma unroll
        for (int i = 0; i < 2; i++)
#pragma unroll
            for (int kf = 0; kf < 2; kf++)
                a[i][kf] = *(const bf16x8*)&As[wr * 32 + i * 16 + lr][kf * 32 + kg * 8];
#pragma unroll
        for (int j = 0; j < 2; j++)
#pragma unroll
            for (int kf = 0; kf < 2; kf++)
                bb[j][kf] = *(const bf16x8*)&Bs[wc * 32 + j * 16 + lr][kf * 32 + kg * 8];
#pragma unroll
        for (int i = 0; i < 2; i++)
#pragma unroll
            for (int j = 0; j < 2; j++) {
                acc[i][j] = __builtin_amdgcn_mfma_f32_16x16x32_bf16(a[i][0], bb[j][0], acc[i][j], 0, 0, 0);
                acc[i][j] = __builtin_amdgcn_mfma_f32_16x16x32_bf16(a[i][1], bb[j][1], acc[i][j], 0, 0, 0);
            }
    }

#pragma unroll
    for (int i = 0; i < 2; i++) {
#pragma unroll
        for (int r = 0; r < 4; r++) {
            int m = bm + wr * 32 + i * 16 + kg * 4 + r;
            if (m >= J.M) continue;
            const float* addrow = nullptr;
            if (J.Add) {
                int bb2 = m / J.addRows; int rr = m - bb2 * J.addRows;
                addrow = J.Add + bb2 * J.addBS + J.addOff + (long)rr * 512;
            }
            float* orow = J.Out + (long)m * 512;
#pragma unroll
            for (int j = 0; j < 2; j++) {
                int n = bn + wc * 32 + j * 16 + lr;
                float v = acc[i][j][r] * J.scale;
                if (J.bias) v += J.bias[n];
                if (J.relu) v = fmaxf(v, 0.f);
                if (addrow) v += addrow[n];
                orow[n] = v;
            }
        }
    }
}

// ---------------- attention 1 (R8-proven): P[b,h,n,q] = softmax_n( q·k ), transposed store ----
__global__ __launch_bounds__(256) void attn1_kernel(const float* __restrict__ qs,
                                                    const float* __restrict__ ks,
                                                    float* __restrict__ P) {
    int bid = blockIdx.x;
    int qi = bid % QL;
    int h = (bid / QL) % HEADS;
    int b = bid / (QL * HEADS);
    __shared__ __align__(16) float qrow[64];
    __shared__ float redm[4], reds[4];
    int tid = threadIdx.x;
    if (tid < 64) qrow[tid] = qs[((long)(b * QL + qi)) * DIM + h * 64 + tid];
    __syncthreads();
    float s = -1e30f;
    if (tid < VS) {
        const float4* kr4 = (const float4*)(ks + ((long)(b * VS + tid)) * DIM + h * 64);
        const float4* q4 = (const float4*)qrow;
        float acc = 0.f;
#pragma unroll
        for (int i = 0; i < 16; i++) {
            float4 kv = kr4[i], qv = q4[i];
            acc += qv.x * kv.x + qv.y * kv.y + qv.z * kv.z + qv.w * kv.w;
        }
        s = acc;
    }
    float wm = waveMax(s);
    if ((tid & 63) == 0) redm[tid >> 6] = wm;
    __syncthreads();
    float m = fmaxf(fmaxf(redm[0], redm[1]), fmaxf(redm[2], redm[3]));
    float e = (tid < VS) ? expf(s - m) : 0.f;
    float ws = waveSum(e);
    if ((tid & 63) == 0) reds[tid >> 6] = ws;
    __syncthreads();
    float tot = reds[0] + reds[1] + reds[2] + reds[3];
    if (tid < VS) P[(((long)(b * HEADS + h)) * VS + tid) * QL + qi] = e / tot;
}

// ---------------- fused conv v5: packed fp32, channel PAIR per lane ----------------
// Block = (b, channel-pair). Channels c0,c0+1 share the same head -> same P row.
// bn scales folded into conv weights. All conv math in v_pk_fma_f32.
#define CSTEPP(N, HAm,HAc,HAp, HBm,HBc,HBp, HCm,HCc,HCp, GAm,GAc,GAp, GBm,GBc,GBp, GCm,GCc,GCp) \
{                                                                                              \
    f32x2 pv = {0.f, 0.f};                                                                     \
    if ((N) < VS) {                                                                            \
        f32x2 vn = vcol2[(N)];                                                                 \
        float ps = 0.f;                                                                        \
        if (qload) ps = Pp[(long)(N) * QL + q];                                                \
        pv.x = ps * vn.x; pv.y = ps * vn.y;                                                    \
    }                                                                                          \
    HCc = pv;                                                                                  \
    HCm.x = __shfl_up(pv.x, 1, 64);   HCm.y = __shfl_up(pv.y, 1, 64);                          \
    HCp.x = __shfl_down(pv.x, 1, 64); HCp.y = __shfl_down(pv.y, 1, 64);                        \
    f32x2 g = {0.f, 0.f};                                                                      \
    if (gok && (N) >= 1 && (N) <= VS) {                                                        \
        f32x2 acc = b1v2;                                                                      \
        acc = pk_fma(HAm, w1p[0], acc); acc = pk_fma(HAc, w1p[1], acc);                        \
        acc = pk_fma(HAp, w1p[2], acc); acc = pk_fma(HBm, w1p[3], acc);                        \
        acc = pk_fma(HBc, w1p[4], acc); acc = pk_fma(HBp, w1p[5], acc);                        \
        acc = pk_fma(HCm, w1p[6], acc); acc = pk_fma(HCc, w1p[7], acc);                        \
        acc = pk_fma(HCp, w1p[8], acc);                                                        \
        g.x = fmaxf(acc.x, 0.f); g.y = fmaxf(acc.y, 0.f);                                      \
    }                                                                                          \
    GCc = g;                                                                                   \
    GCm.x = __shfl_up(g.x, 1, 64);   GCm.y = __shfl_up(g.y, 1, 64);                            \
    GCp.x = __shfl_down(g.x, 1, 64); GCp.y = __shfl_down(g.y, 1, 64);                          \
    if ((N) >= 2) {                                                                            \
        f32x2 a2 = b2v2;                                                                       \
        a2 = pk_fma(GAm, w2p[0], a2); a2 = pk_fma(GAc, w2p[1], a2);                            \
        a2 = pk_fma(GAp, w2p[2], a2); a2 = pk_fma(GBm, w2p[3], a2);                            \
        a2 = pk_fma(GBc, w2p[4], a2); a2 = pk_fma(GBp, w2p[5], a2);                            \
        a2 = pk_fma(GCm, w2p[6], a2); a2 = pk_fma(GCc, w2p[7], a2);                            \
        a2 = pk_fma(GCp, w2p[8], a2);                                                          \
        csum.x += fmaxf(a2.x, 0.f); csum.y += fmaxf(a2.y, 0.f);                                \
    }                                                                                          \
}

__global__ __launch_bounds__(256) void conv_pk_kernel(
    const float* __restrict__ P, const float* __restrict__ vs,
    const float* __restrict__ dw1, const float* __restrict__ dw2,
    const float* __restrict__ bn1g, const float* __restrict__ bn1b,
    const float* __restrict__ bn1m, const float* __restrict__ bn1v,
    const float* __restrict__ bn2g, const float* __restrict__ bn2b,
    const float* __restrict__ bn2m, const float* __restrict__ bn2v,
    float* __restrict__ m2) {
    int bc = blockIdx.x;            // 1024 = 4 b x 256 channel-pairs
    int c0 = (bc & 255) * 2;
    int b = bc >> 8;
    int h = c0 >> 6;                // c0, c0+1 share this head
    int tid = threadIdx.x;
    int wave = tid >> 6, lane = tid & 63;
    int q = wave * 60 + lane - 2;
    bool qload = (q >= 0 && q < QL);
    bool gok = (lane >= 1 && lane <= 62 && q >= 0 && q < QL);
    bool outok = (lane >= 2 && lane <= 61 && q < QL);
    __shared__ __align__(8) f32x2 vcol2[VS];
    if (tid < VS) {
        const float* vp = vs + ((long)(b * VS + tid)) * DIM + c0;
        f32x2 t; t.x = vp[0]; t.y = vp[1];
        vcol2[tid] = t;
    }
    float s1x = bn1g[c0]     * rsqrtf(bn1v[c0]     + EPS_BN);
    float s1y = bn1g[c0 + 1] * rsqrtf(bn1v[c0 + 1] + EPS_BN);
    float s2x = bn2g[c0]     * rsqrtf(bn2v[c0]     + EPS_BN);
    float s2y = bn2g[c0 + 1] * rsqrtf(bn2v[c0 + 1] + EPS_BN);
    f32x2 b1v2; b1v2.x = bn1b[c0] - bn1m[c0] * s1x; b1v2.y = bn1b[c0 + 1] - bn1m[c0 + 1] * s1y;
    f32x2 b2v2; b2v2.x = bn2b[c0] - bn2m[c0] * s2x; b2v2.y = bn2b[c0 + 1] - bn2m[c0 + 1] * s2y;
    f32x2 w1p[9], w2p[9];
#pragma unroll
    for (int i = 0; i < 9; i++) {
        w1p[i].x = dw1[c0 * 9 + i] * s1x;       w1p[i].y = dw1[(c0 + 1) * 9 + i] * s1y;
        w2p[i].x = dw2[c0 * 9 + i] * s2x;       w2p[i].y = dw2[(c0 + 1) * 9 + i] * s2y;
    }
    const float* Pp = P + ((long)(b * HEADS + h)) * VS * QL;
    __syncthreads();
    f32x2 z2 = {0.f, 0.f};
    f32x2 HAm = z2, HAc = z2, HAp = z2, HBm = z2, HBc = z2, HBp = z2, HCm = z2, HCc = z2, HCp = z2;
    f32x2 GAm = z2, GAc = z2, GAp = z2, GBm = z2, GBc = z2, GBp = z2, GCm = z2, GCc = z2, GCp = z2;
    f32x2 csum = z2;
    for (int nb = 0; nb < 198; nb += 3) {
        CSTEPP(nb,     HAm,HAc,HAp, HBm,HBc,HBp, HCm,HCc,HCp, GAm,GAc,GAp, GBm,GBc,GBp, GCm,GCc,GCp)
        CSTEPP(nb + 1, HBm,HBc,HBp, HCm,HCc,HCp, HAm,HAc,HAp, GBm,GBc,GBp, GCm,GCc,GCp, GAm,GAc,GAp)
        CSTEPP(nb + 2, HCm,HCc,HCp, HAm,HAc,HAp, HBm,HBc,HBp, GCm,GCc,GCp, GAm,GAc,GAp, GBm,GBc,GBp)
    }
    if (outok) {
        const float inv = 1.f / (float)VS;
        f32x2 o; o.x = csum.x * inv; o.y = csum.y * inv;
        *(f32x2*)&m2[((long)(b * QL + q)) * DIM + c0] = o;
    }
}

// ---------------- attention 2 via MFMA (R10-proven) ----------------
__global__ __launch_bounds__(256) void attn2_mfma(const float* __restrict__ Qm,
                                                  const float* __restrict__ Km,
                                                  const float* __restrict__ Vm,
                                                  float* __restrict__ O) {
    int bid = blockIdx.x;          // 128 = b(4) x h(8) x nq(4)
    int nq = bid & 3;
    int h = (bid >> 2) & 7;
    int b = bid >> 5;
    int n0 = nq * 64;
    int tid = threadIdx.x;
    int wave = tid >> 6, lane = tid & 63;
    int lr = lane & 15, kg = lane >> 4;

    __shared__ __align__(16) char smem[77568];
    ushort (*VT)[264] = (ushort(*)[264])smem;            // [64][264]  VT[d][q]
    ushort (*Qb)[72]  = (ushort(*)[72])(smem + 33792);   // [64][72]
    ushort (*Kb)[72]  = (ushort(*)[72])(smem + 43008);   // [240][72]
    ushort (*Pl)[264] = (ushort(*)[264])(smem + 33792);  // [64][264] aliases Qb/Kb

    const long qmBase = ((long)(b * VS)) * DIM + h * 64;
    const long kmBase = ((long)(b * QL)) * DIM + h * 64;

    {
        int r = tid >> 2, c0 = (tid & 3) * 16;
        int n = min(n0 + r, VS - 1);
        const float* src = Qm + qmBase + (long)n * DIM + c0;
        *(uint4*)&Qb[r][c0]     = ld_cvt8(src);
        *(uint4*)&Qb[r][c0 + 8] = ld_cvt8(src + 8);
    }
    {
        int c0 = (tid & 3) * 16;
#pragma unroll
        for (int i = 0; i < 4; i++) {
            int r = (tid >> 2) + 64 * i;
            if (r < 240) {
                uint4 lo = {0u,0u,0u,0u}, hi = {0u,0u,0u,0u};
                if (r < QL) {
                    const float* src = Km + kmBase + (long)r * DIM + c0;
                    lo = ld_cvt8(src); hi = ld_cvt8(src + 8);
                }
                *(uint4*)&Kb[r][c0]     = lo;
                *(uint4*)&Kb[r][c0 + 8] = hi;
            }
        }
    }
    {
        int c0 = (tid & 3) * 16;
#pragma unroll
        for (int i = 0; i < 4; i++) {
            int qq = (tid >> 2) + 64 * i;
            if (qq < 240) {
                ushort u[16];
                if (qq < QL) {
                    const float* src = Vm + kmBase + (long)qq * DIM + c0;
                    *(uint4*)&u[0] = ld_cvt8(src);
                    *(uint4*)&u[8] = ld_cvt8(src + 8);
                } else {
#pragma unroll
                    for (int j = 0; j < 16; j++) u[j] = 0;
                }
#pragma unroll
                for (int j = 0; j < 16; j++) VT[c0 + j][qq] = u[j];
            }
        }
        int d = tid >> 2, qz = 240 + (tid & 3) * 4;
#pragma unroll
        for (int j = 0; j < 4; j++) VT[d][qz + j] = 0;
    }
    __syncthreads();

    bf16x8 a0 = *(const bf16x8*)&Qb[wave * 16 + lr][kg * 8];
    bf16x8 a1 = *(const bf16x8*)&Qb[wave * 16 + lr][32 + kg * 8];
    f32x4 sc[15];
#pragma unroll
    for (int ct = 0; ct < 15; ct++) {
        bf16x8 b0 = *(const bf16x8*)&Kb[ct * 16 + lr][kg * 8];
        bf16x8 b1 = *(const bf16x8*)&Kb[ct * 16 + lr][32 + kg * 8];
        f32x4 z = {0.f, 0.f, 0.f, 0.f};
        z = __builtin_amdgcn_mfma_f32_16x16x32_bf16(a0, b0, z, 0, 0, 0);
        z = __builtin_amdgcn_mfma_f32_16x16x32_bf16(a1, b1, z, 0, 0, 0);
        sc[ct] = z;
    }
    __syncthreads();

    const float scl = 0.044194173824159216f;
    float pinv[4];
#pragma unroll
    for (int r = 0; r < 4; r++) {
        float m = -1e30f;
#pragma unroll
        for (int ct = 0; ct < 15; ct++) {
            float v = sc[ct][r] * scl;
            if (ct * 16 + lr >= QL) v = -1e30f;
            sc[ct][r] = v;
            m = fmaxf(m, v);
        }
#pragma unroll
        for (int o = 1; o < 16; o <<= 1) m = fmaxf(m, __shfl_xor(m, o, 64));
        float s = 0.f;
#pragma unroll
        for (int ct = 0; ct < 15; ct++) {
            float e = expf(sc[ct][r] - m);
            sc[ct][r] = e;
            s += e;
        }
#pragma unroll
        for (int o = 1; o < 16; o <<= 1) s += __shfl_xor(s, o, 64);
        pinv[r] = 1.f / s;
    }
#pragma unroll
    for (int r = 0; r < 4; r++) {
        int row = wave * 16 + (lane >> 4) * 4 + r;
#pragma unroll
        for (int ct = 0; ct < 15; ct++) {
            float p = sc[ct][r] * pinv[r];
            Pl[row][ct * 16 + lr] = (ushort)(cvt_pk_bf16(p, p) & 0xffffu);
        }
        Pl[row][240 + lr] = 0;
    }
    __syncthreads();

    bf16x8 pa[8];
#pragma unroll
    for (int ks = 0; ks < 8; ks++)
        pa[ks] = *(const bf16x8*)&Pl[wave * 16 + lr][ks * 32 + kg * 8];
    f32x4 ov[4] = {};
#pragma unroll
    for (int dt = 0; dt < 4; dt++)
#pragma unroll
        for (int ks = 0; ks < 8; ks++) {
            bf16x8 vb = *(const bf16x8*)&VT[dt * 16 + lr][ks * 32 + kg * 8];
            ov[dt] = __builtin_amdgcn_mfma_f32_16x16x32_bf16(pa[ks], vb, ov[dt], 0, 0, 0);
        }

#pragma unroll
    for (int dt = 0; dt < 4; dt++)
#pragma unroll
        for (int r = 0; r < 4; r++) {
            int n = n0 + wave * 16 + (lane >> 4) * 4 + r;
            if (n < VS) {
                long addr = qmBase + (long)n * DIM + dt * 16 + lr;
                O[addr] = Qm[addr] + ov[dt][r];
            }
        }
}

static inline GJob mkjob(const float* A, int aRows, long aBS, long aOff,
                         const float* W, const float* bias,
                         const float* Add, int addRows, long addBS, long addOff,
                         float* Out, int M, float scale, int relu) {
    GJob j;
    j.A = A; j.W = W; j.bias = bias; j.Add = Add; j.Out = Out;
    j.aBS = aBS; j.aOff = aOff; j.addBS = addBS; j.addOff = addOff;
    j.aRows = aRows; j.addRows = addRows; j.M = M; j.relu = relu;
    j.scale = scale; j.pad0 = j.pad1 = j.pad2 = 0;
    return j;
}

extern "C" void kernel_launch(void* const* d_in, const int* in_sizes, int n_in,
                              void* d_out, int out_size, void* d_ws, size_t ws_size,
                              hipStream_t stream) {
    const float* x     = (const float*)d_in[0];
    const float* Wq    = (const float*)d_in[1];
    const float* Wk    = (const float*)d_in[2];
    const float* Wv    = (const float*)d_in[3];
    const float* Wproj = (const float*)d_in[4];
    const float* bproj = (const float*)d_in[5];
    const float* dw1   = (const float*)d_in[6];
    const float* dw2   = (const float*)d_in[7];
    const float* pw    = (const float*)d_in[8];
    const float* bn1g  = (const float*)d_in[9];
    const float* bn1b  = (const float*)d_in[10];
    const float* bn1m  = (const float*)d_in[11];
    const float* bn1v  = (const float*)d_in[12];
    const float* bn2g  = (const float*)d_in[13];
    const float* bn2b  = (const float*)d_in[14];
    const float* bn2m  = (const float*)d_in[15];
    const float* bn2v  = (const float*)d_in[16];
    const float* mWq   = (const float*)d_in[17];
    const float* mbq   = (const float*)d_in[18];
    const float* mWk   = (const float*)d_in[19];
    const float* mbk   = (const float*)d_in[20];
    const float* mWv   = (const float*)d_in[21];
    const float* mbv   = (const float*)d_in[22];
    const float* mWo   = (const float*)d_in[23];
    const float* mbo   = (const float*)d_in[24];

    float* ws = (float*)d_ws;
    // Overlay (floats):
    //   qs @ 0 (460800) -> m2 -> Km
    //   ks @ 460800 (401408) -> O
    //   vsb @ 862208 (401408) -> O2
    //   P @ 1263616 (1411200) -> [kc @ +0 | Qm @ +460800 | Vm @ +862208]
    float* qs = ws;
    float* ks = ws + 460800;
    float* vsb = ws + 862208;
    float* P  = ws + 1263616;
    float* m2 = ws;
    float* kc = ws + 1263616;
    float* Qm = ws + 1263616 + 460800;
    float* Vm = ws + 1263616 + 460800 + 401408;
    float* Km = ws;
    float* O  = ws + 460800;
    float* O2 = ws + 862208;

    const long xBS = 421L * DIM;
    const long clsOff = 196L * DIM;

    dim3 blk(256);

    // L1: q,k,v projections fused (360 blocks)
    {
        GJobs js;
        js.j[0] = mkjob(x, QL, xBS, clsOff, Wq, nullptr, nullptr, 1, 0, 0, qs, 900, 0.125f, 0);
        js.j[1] = mkjob(x, VS, xBS, 0, Wk, nullptr, nullptr, 1, 0, 0, ks, 784, 1.f, 0);
        js.j[2] = mkjob(x, VS, xBS, 0, Wv, nullptr, nullptr, 1, 0, 0, vsb, 784, 1.f, 0);
        js.j[3] = js.j[0];
        gemm_multi<0><<<dim3(8, 15, 3), blk, 0, stream>>>(js);
    }
    attn1_kernel<<<BATCH * HEADS * QL, blk, 0, stream>>>(qs, ks, P);
    conv_pk_kernel<<<BATCH * 256, blk, 0, stream>>>(P, vsb, dw1, dw2,
                                                    bn1g, bn1b, bn1m, bn1v,
                                                    bn2g, bn2b, bn2m, bn2v, m2);
    // L2: kc = cls_cat + m2 @ pw^T  AND  Qm = x_sem @ mWq^T + mbq   (P dead now)
    {
        GJobs js;
        js.j[0] = mkjob(m2, 900, 0, 0, pw, nullptr, x, QL, xBS, clsOff, kc, 900, 1.f, 0);
        js.j[1] = mkjob(x, VS, xBS, 0, mWq, mbq, nullptr, 1, 0, 0, Qm, 784, 1.f, 0);
        js.j[2] = js.j[3] = js.j[0];
        gemm_multi<1><<<dim3(8, 15, 2), blk, 0, stream>>>(js);
    }
    // L3: Km, Vm off kc
    {
        GJobs js;
        js.j[0] = mkjob(kc, 900, 0, 0, mWk, mbk, nullptr, 1, 0, 0, Km, 900, 1.f, 0);
        js.j[1] = mkjob(kc, 900, 0, 0, mWv, mbv, nullptr, 1, 0, 0, Vm, 900, 1.f, 0);
        js.j[2] = js.j[3] = js.j[0];
        gemm_multi<2><<<dim3(8, 15, 2), blk, 0, stream>>>(js);
    }
    attn2_mfma<<<BATCH * HEADS * 4, blk, 0, stream>>>(Qm, Km, Vm, O);
    // L4: O2 = O + relu(O @ mWo^T + mbo)
    {
        GJobs js;
        js.j[0] = mkjob(O, 784, 0, 0, mWo, mbo, O, 784, 0, 0, O2, 784, 1.f, 1);
        js.j[1] = js.j[2] = js.j[3] = js.j[0];
        gemm_multi<3><<<dim3(8, 13, 1), blk, 0, stream>>>(js);
    }
    // L5: out = O2 @ Wproj^T + bproj
    {
        GJobs js;
        js.j[0] = mkjob(O2, 784, 0, 0, Wproj, bproj, nullptr, 1, 0, 0, (float*)d_out, 784, 1.f, 0);
        js.j[1] = js.j[2] = js.j[3] = js.j[0];
        gemm_multi<4><<<dim3(8, 13, 1), blk, 0, stream>>>(js);
    }
}

// Round 12
// 223.777 us; speedup vs baseline: 1.6285x; 1.0687x over previous
//
#include <hip/hip_runtime.h>
#include <math.h>

#define DIM 512
#define HEADS 8
#define QL 225
#define VS 196
#define BATCH 4
#define EPS_BN 1e-5f

typedef __attribute__((ext_vector_type(8))) short bf16x8;
typedef __attribute__((ext_vector_type(4))) float f32x4;
typedef __attribute__((ext_vector_type(2))) float f32x2;

// ---------------- wave (64-lane) reductions ----------------
__device__ __forceinline__ float waveMax(float v) {
#pragma unroll
    for (int o = 32; o; o >>= 1) v = fmaxf(v, __shfl_xor(v, o, 64));
    return v;
}
__device__ __forceinline__ float waveSum(float v) {
#pragma unroll
    for (int o = 32; o; o >>= 1) v += __shfl_xor(v, o, 64);
    return v;
}

// ---------------- packed fp32 ops (CDNA VOP3P) ----------------
__device__ __forceinline__ f32x2 pk_fma(f32x2 a, f32x2 b, f32x2 c) {
    f32x2 d;
    asm("v_pk_fma_f32 %0, %1, %2, %3" : "=v"(d) : "v"(a), "v"(b), "v"(c));
    return d;
}
__device__ __forceinline__ f32x2 pk_mul(f32x2 a, f32x2 b) {
    f32x2 d;
    asm("v_pk_mul_f32 %0, %1, %2" : "=v"(d) : "v"(a), "v"(b));
    return d;
}
__device__ __forceinline__ f32x2 pk_add(f32x2 a, f32x2 b) {
    f32x2 d;
    asm("v_pk_add_f32 %0, %1, %2" : "=v"(d) : "v"(a), "v"(b));
    return d;
}
__device__ __forceinline__ f32x2 pk_max0(f32x2 a) {
    f32x2 d;
    d.x = fmaxf(a.x, 0.f); d.y = fmaxf(a.y, 0.f);
    return d;
}

// ---------------- fp32 -> bf16 pack helpers ----------------
__device__ __forceinline__ unsigned cvt_pk_bf16(float lo, float hi) {
    unsigned r;
    asm("v_cvt_pk_bf16_f32 %0, %1, %2" : "=v"(r) : "v"(lo), "v"(hi));
    return r;
}
__device__ __forceinline__ uint4 ld_cvt8(const float* p) {
    float4 x = *(const float4*)p;
    float4 y = *(const float4*)(p + 4);
    uint4 r;
    r.x = cvt_pk_bf16(x.x, x.y);
    r.y = cvt_pk_bf16(x.z, x.w);
    r.z = cvt_pk_bf16(y.x, y.y);
    r.w = cvt_pk_bf16(y.z, y.w);
    return r;
}

// ---------------- multi-job bf16-MFMA GEMM (N=K=512): Out = scale*A@W^T (+bias)(relu)(+Add) ----
struct GJob {
    const float* A; const float* W; const float* bias; const float* Add; float* Out;
    long aBS, aOff, addBS, addOff;
    int aRows, addRows, M, relu;
    float scale; int pad0, pad1, pad2;
};
struct GJobs { GJob j[4]; };

template<int LAYER>
__global__ __launch_bounds__(256) void gemm_multi(GJobs jobs) {
    const GJob J = jobs.j[blockIdx.z];
    const int bm = blockIdx.y * 64, bn = blockIdx.x * 64;
    if (bm >= J.M) return;
    __shared__ __align__(16) ushort As[64][72];
    __shared__ __align__(16) ushort Bs[64][72];
    const int tid = threadIdx.x;
    const int srow = tid >> 2, skq = tid & 3;
    const float* ap = nullptr;
    {
        int m = bm + srow;
        if (m < J.M) { int bb = m / J.aRows; int r = m - bb * J.aRows;
                       ap = J.A + bb * J.aBS + J.aOff + (long)r * 512 + skq * 16; }
    }
    const float* bp = J.W + (long)(bn + srow) * 512 + skq * 16;

    const int lane = tid & 63, wid = tid >> 6;
    const int wr = wid >> 1, wc = wid & 1;
    const int lr = lane & 15, kg = lane >> 4;

    f32x4 acc[2][2] = {};

    uint4 a01 = {0u,0u,0u,0u}, a23 = {0u,0u,0u,0u};
    if (ap) { a01 = ld_cvt8(ap); a23 = ld_cvt8(ap + 8); }
    uint4 b01 = ld_cvt8(bp), b23 = ld_cvt8(bp + 8);

    for (int kt = 0; kt < 512; kt += 64) {
        __syncthreads();
        *(uint4*)&As[srow][skq * 16]     = a01;
        *(uint4*)&As[srow][skq * 16 + 8] = a23;
        *(uint4*)&Bs[srow][skq * 16]     = b01;
        *(uint4*)&Bs[srow][skq * 16 + 8] = b23;
        __syncthreads();
        if (kt + 64 < 512) {
            if (ap) { a01 = ld_cvt8(ap + kt + 64); a23 = ld_cvt8(ap + kt + 72); }
            b01 = ld_cvt8(bp + kt + 64); b23 = ld_cvt8(bp + kt + 72);
        }
        bf16x8 a[2][2], bb[2][2];
#pragma unroll
        for (int i = 0; i < 2; i++)
#pragma unroll
            for (int kf = 0; kf < 2; kf++)
                a[i][kf] = *(const bf16x8*)&As[wr * 32 + i * 16 + lr][kf * 32 + kg * 8];
#pragma unroll
        for (int j = 0; j < 2; j++)
#pragma unroll
            for (int kf = 0; kf < 2; kf++)
                bb[j][kf] = *(const bf16x8*)&Bs[wc * 32 + j * 16 + lr][kf * 32 + kg * 8];
#pragma unroll
        for (int i = 0; i < 2; i++)
#pragma unroll
            for (int j = 0; j < 2; j++) {
                acc[i][j] = __builtin_amdgcn_mfma_f32_16x16x32_bf16(a[i][0], bb[j][0], acc[i][j], 0, 0, 0);
                acc[i][j] = __builtin_amdgcn_mfma_f32_16x16x32_bf16(a[i][1], bb[j][1], acc[i][j], 0, 0, 0);
            }
    }

#pragma unroll
    for (int i = 0; i < 2; i++) {
#pragma unroll
        for (int r = 0; r < 4; r++) {
            int m = bm + wr * 32 + i * 16 + kg * 4 + r;
            if (m >= J.M) continue;
            const float* addrow = nullptr;
            if (J.Add) {
                int bb2 = m / J.addRows; int rr = m - bb2 * J.addRows;
                addrow = J.Add + bb2 * J.addBS + J.addOff + (long)rr * 512;
            }
            float* orow = J.Out + (long)m * 512;
#pragma unroll
            for (int j = 0; j < 2; j++) {
                int n = bn + wc * 32 + j * 16 + lr;
                float v = acc[i][j][r] * J.scale;
                if (J.bias) v += J.bias[n];
                if (J.relu) v = fmaxf(v, 0.f);
                if (addrow) v += addrow[n];
                orow[n] = v;
            }
        }
    }
}

// ---------------- attention 1 (R8-proven): P[b,h,n,q] = softmax_n( q·k ), transposed store ----
__global__ __launch_bounds__(256) void attn1_kernel(const float* __restrict__ qs,
                                                    const float* __restrict__ ks,
                                                    float* __restrict__ P) {
    int bid = blockIdx.x;
    int qi = bid % QL;
    int h = (bid / QL) % HEADS;
    int b = bid / (QL * HEADS);
    __shared__ __align__(16) float qrow[64];
    __shared__ float redm[4], reds[4];
    int tid = threadIdx.x;
    if (tid < 64) qrow[tid] = qs[((long)(b * QL + qi)) * DIM + h * 64 + tid];
    __syncthreads();
    float s = -1e30f;
    if (tid < VS) {
        const float4* kr4 = (const float4*)(ks + ((long)(b * VS + tid)) * DIM + h * 64);
        const float4* q4 = (const float4*)qrow;
        float acc = 0.f;
#pragma unroll
        for (int i = 0; i < 16; i++) {
            float4 kv = kr4[i], qv = q4[i];
            acc += qv.x * kv.x + qv.y * kv.y + qv.z * kv.z + qv.w * kv.w;
        }
        s = acc;
    }
    float wm = waveMax(s);
    if ((tid & 63) == 0) redm[tid >> 6] = wm;
    __syncthreads();
    float m = fmaxf(fmaxf(redm[0], redm[1]), fmaxf(redm[2], redm[3]));
    float e = (tid < VS) ? expf(s - m) : 0.f;
    float ws = waveSum(e);
    if ((tid & 63) == 0) reds[tid >> 6] = ws;
    __syncthreads();
    float tot = reds[0] + reds[1] + reds[2] + reds[3];
    if (tid < VS) P[(((long)(b * HEADS + h)) * VS + tid) * QL + qi] = e / tot;
}

// ---------------- fused conv v6: packed channel-pair + producer partials + P prefetch ----
// When h row N is produced, fold its horizontal taps into 3 weighted partial row-sums
// (top/mid/bot roles). g(N-1) = bot(N) + mid(N-1) + top(N-2): 3 pk_adds.
// Same for conv2. P scalars for body k+1 prefetched during body k.
__device__ __forceinline__ float ldP(const float* Pp, int N, int q, bool qload) {
    float ps = 0.f;
    if (qload && N < VS) ps = Pp[(long)N * QL + q];
    return ps;
}

#define CSTEP6(N, PS, TAw,TAm2, TBw,TBm1, UAw,UAm2, UBw,UBm1)                      \
{                                                                                  \
    f32x2 vn = vcol2[(N)];                                                         \
    f32x2 pv; pv.x = (PS) * vn.x; pv.y = (PS) * vn.y;                              \
    f32x2 hm, hp;                                                                  \
    hm.x = __shfl_up(pv.x, 1, 64);   hm.y = __shfl_up(pv.y, 1, 64);                \
    hp.x = __shfl_down(pv.x, 1, 64); hp.y = __shfl_down(pv.y, 1, 64);              \
    f32x2 g = z2;                                                                  \
    if (gok && (N) >= 1 && (N) <= VS) {                                            \
        f32x2 tC = pk_fma(hp, w1p[8], pk_fma(pv, w1p[7], pk_mul(hm, w1p[6])));     \
        f32x2 s = pk_add(tC, pk_add(TBm1, pk_add(TAm2, b1v2)));                    \
        g = pk_max0(s);                                                            \
    }                                                                              \
    TAw = pk_fma(hp, w1p[2], pk_fma(pv, w1p[1], pk_mul(hm, w1p[0])));              \
    TBw = pk_fma(hp, w1p[5], pk_fma(pv, w1p[4], pk_mul(hm, w1p[3])));              \
    f32x2 gm, gp;                                                                  \
    gm.x = __shfl_up(g.x, 1, 64);   gm.y = __shfl_up(g.y, 1, 64);                  \
    gp.x = __shfl_down(g.x, 1, 64); gp.y = __shfl_down(g.y, 1, 64);                \
    if ((N) >= 2) {                                                                \
        f32x2 uC = pk_fma(gp, w2p[8], pk_fma(g, w2p[7], pk_mul(gm, w2p[6])));      \
        f32x2 s2 = pk_add(uC, pk_add(UBm1, pk_add(UAm2, b2v2)));                   \
        csum = pk_add(csum, pk_max0(s2));                                          \
    }                                                                              \
    UAw = pk_fma(gp, w2p[2], pk_fma(g, w2p[1], pk_mul(gm, w2p[0])));               \
    UBw = pk_fma(gp, w2p[5], pk_fma(g, w2p[4], pk_mul(gm, w2p[3])));               \
}

__global__ __launch_bounds__(256) void conv_pk_kernel(
    const float* __restrict__ P, const float* __restrict__ vs,
    const float* __restrict__ dw1, const float* __restrict__ dw2,
    const float* __restrict__ bn1g, const float* __restrict__ bn1b,
    const float* __restrict__ bn1m, const float* __restrict__ bn1v,
    const float* __restrict__ bn2g, const float* __restrict__ bn2b,
    const float* __restrict__ bn2m, const float* __restrict__ bn2v,
    float* __restrict__ m2) {
    int bc = blockIdx.x;            // 1024 = 4 b x 256 channel-pairs
    int c0 = (bc & 255) * 2;
    int b = bc >> 8;
    int h = c0 >> 6;                // c0, c0+1 share this head
    int tid = threadIdx.x;
    int wave = tid >> 6, lane = tid & 63;
    int q = wave * 60 + lane - 2;
    bool qload = (q >= 0 && q < QL);
    bool gok = (lane >= 1 && lane <= 62 && q >= 0 && q < QL);
    bool outok = (lane >= 2 && lane <= 61 && q < QL);
    __shared__ __align__(8) f32x2 vcol2[200];   // zero-padded past VS
    if (tid < 200) {
        f32x2 t = {0.f, 0.f};
        if (tid < VS) {
            const float* vp = vs + ((long)(b * VS + tid)) * DIM + c0;
            t.x = vp[0]; t.y = vp[1];
        }
        vcol2[tid] = t;
    }
    float s1x = bn1g[c0]     * rsqrtf(bn1v[c0]     + EPS_BN);
    float s1y = bn1g[c0 + 1] * rsqrtf(bn1v[c0 + 1] + EPS_BN);
    float s2x = bn2g[c0]     * rsqrtf(bn2v[c0]     + EPS_BN);
    float s2y = bn2g[c0 + 1] * rsqrtf(bn2v[c0 + 1] + EPS_BN);
    f32x2 b1v2; b1v2.x = bn1b[c0] - bn1m[c0] * s1x; b1v2.y = bn1b[c0 + 1] - bn1m[c0 + 1] * s1y;
    f32x2 b2v2; b2v2.x = bn2b[c0] - bn2m[c0] * s2x; b2v2.y = bn2b[c0 + 1] - bn2m[c0 + 1] * s2y;
    f32x2 w1p[9], w2p[9];
#pragma unroll
    for (int i = 0; i < 9; i++) {
        w1p[i].x = dw1[c0 * 9 + i] * s1x;       w1p[i].y = dw1[(c0 + 1) * 9 + i] * s1y;
        w2p[i].x = dw2[c0 * 9 + i] * s2x;       w2p[i].y = dw2[(c0 + 1) * 9 + i] * s2y;
    }
    const float* Pp = P + ((long)(b * HEADS + h)) * VS * QL;
    __syncthreads();
    const f32x2 z2 = {0.f, 0.f};
    f32x2 tAa = z2, tAb = z2, tAc = z2, tBa = z2, tBb = z2, tBc = z2;
    f32x2 uAa = z2, uAb = z2, uAc = z2, uBa = z2, uBb = z2, uBc = z2;
    f32x2 csum = z2;
    float ps0 = ldP(Pp, 0, q, qload);
    float ps1 = ldP(Pp, 1, q, qload);
    float ps2 = ldP(Pp, 2, q, qload);
    for (int nb = 0; nb < 198; nb += 3) {
        // prefetch next body's P scalars (latency hides under this body's compute)
        float pn0 = ldP(Pp, nb + 3, q, qload);
        float pn1 = ldP(Pp, nb + 4, q, qload);
        float pn2 = ldP(Pp, nb + 5, q, qload);
        CSTEP6(nb,     ps0, tAa,tAb, tBa,tBc, uAa,uAb, uBa,uBc)
        CSTEP6(nb + 1, ps1, tAb,tAc, tBb,tBa, uAb,uAc, uBb,uBa)
        CSTEP6(nb + 2, ps2, tAc,tAa, tBc,tBb, uAc,uAa, uBc,uBb)
        ps0 = pn0; ps1 = pn1; ps2 = pn2;
    }
    if (outok) {
        const float inv = 1.f / (float)VS;
        f32x2 o; o.x = csum.x * inv; o.y = csum.y * inv;
        *(f32x2*)&m2[((long)(b * QL + q)) * DIM + c0] = o;
    }
}

// ---------------- attention 2 via MFMA (R10-proven) ----------------
__global__ __launch_bounds__(256) void attn2_mfma(const float* __restrict__ Qm,
                                                  const float* __restrict__ Km,
                                                  const float* __restrict__ Vm,
                                                  float* __restrict__ O) {
    int bid = blockIdx.x;          // 128 = b(4) x h(8) x nq(4)
    int nq = bid & 3;
    int h = (bid >> 2) & 7;
    int b = bid >> 5;
    int n0 = nq * 64;
    int tid = threadIdx.x;
    int wave = tid >> 6, lane = tid & 63;
    int lr = lane & 15, kg = lane >> 4;

    __shared__ __align__(16) char smem[77568];
    ushort (*VT)[264] = (ushort(*)[264])smem;            // [64][264]  VT[d][q]
    ushort (*Qb)[72]  = (ushort(*)[72])(smem + 33792);   // [64][72]
    ushort (*Kb)[72]  = (ushort(*)[72])(smem + 43008);   // [240][72]
    ushort (*Pl)[264] = (ushort(*)[264])(smem + 33792);  // [64][264] aliases Qb/Kb

    const long qmBase = ((long)(b * VS)) * DIM + h * 64;
    const long kmBase = ((long)(b * QL)) * DIM + h * 64;

    {
        int r = tid >> 2, c0 = (tid & 3) * 16;
        int n = min(n0 + r, VS - 1);
        const float* src = Qm + qmBase + (long)n * DIM + c0;
        *(uint4*)&Qb[r][c0]     = ld_cvt8(src);
        *(uint4*)&Qb[r][c0 + 8] = ld_cvt8(src + 8);
    }
    {
        int c0 = (tid & 3) * 16;
#pragma unroll
        for (int i = 0; i < 4; i++) {
            int r = (tid >> 2) + 64 * i;
            if (r < 240) {
                uint4 lo = {0u,0u,0u,0u}, hi = {0u,0u,0u,0u};
                if (r < QL) {
                    const float* src = Km + kmBase + (long)r * DIM + c0;
                    lo = ld_cvt8(src); hi = ld_cvt8(src + 8);
                }
                *(uint4*)&Kb[r][c0]     = lo;
                *(uint4*)&Kb[r][c0 + 8] = hi;
            }
        }
    }
    {
        int c0 = (tid & 3) * 16;
#pragma unroll
        for (int i = 0; i < 4; i++) {
            int qq = (tid >> 2) + 64 * i;
            if (qq < 240) {
                ushort u[16];
                if (qq < QL) {
                    const float* src = Vm + kmBase + (long)qq * DIM + c0;
                    *(uint4*)&u[0] = ld_cvt8(src);
                    *(uint4*)&u[8] = ld_cvt8(src + 8);
                } else {
#pragma unroll
                    for (int j = 0; j < 16; j++) u[j] = 0;
                }
#pragma unroll
                for (int j = 0; j < 16; j++) VT[c0 + j][qq] = u[j];
            }
        }
        int d = tid >> 2, qz = 240 + (tid & 3) * 4;
#pragma unroll
        for (int j = 0; j < 4; j++) VT[d][qz + j] = 0;
    }
    __syncthreads();

    bf16x8 a0 = *(const bf16x8*)&Qb[wave * 16 + lr][kg * 8];
    bf16x8 a1 = *(const bf16x8*)&Qb[wave * 16 + lr][32 + kg * 8];
    f32x4 sc[15];
#pragma unroll
    for (int ct = 0; ct < 15; ct++) {
        bf16x8 b0 = *(const bf16x8*)&Kb[ct * 16 + lr][kg * 8];
        bf16x8 b1 = *(const bf16x8*)&Kb[ct * 16 + lr][32 + kg * 8];
        f32x4 z = {0.f, 0.f, 0.f, 0.f};
        z = __builtin_amdgcn_mfma_f32_16x16x32_bf16(a0, b0, z, 0, 0, 0);
        z = __builtin_amdgcn_mfma_f32_16x16x32_bf16(a1, b1, z, 0, 0, 0);
        sc[ct] = z;
    }
    __syncthreads();

    const float scl = 0.044194173824159216f;
    float pinv[4];
#pragma unroll
    for (int r = 0; r < 4; r++) {
        float m = -1e30f;
#pragma unroll
        for (int ct = 0; ct < 15; ct++) {
            float v = sc[ct][r] * scl;
            if (ct * 16 + lr >= QL) v = -1e30f;
            sc[ct][r] = v;
            m = fmaxf(m, v);
        }
#pragma unroll
        for (int o = 1; o < 16; o <<= 1) m = fmaxf(m, __shfl_xor(m, o, 64));
        float s = 0.f;
#pragma unroll
        for (int ct = 0; ct < 15; ct++) {
            float e = expf(sc[ct][r] - m);
            sc[ct][r] = e;
            s += e;
        }
#pragma unroll
        for (int o = 1; o < 16; o <<= 1) s += __shfl_xor(s, o, 64);
        pinv[r] = 1.f / s;
    }
#pragma unroll
    for (int r = 0; r < 4; r++) {
        int row = wave * 16 + (lane >> 4) * 4 + r;
#pragma unroll
        for (int ct = 0; ct < 15; ct++) {
            float p = sc[ct][r] * pinv[r];
            Pl[row][ct * 16 + lr] = (ushort)(cvt_pk_bf16(p, p) & 0xffffu);
        }
        Pl[row][240 + lr] = 0;
    }
    __syncthreads();

    bf16x8 pa[8];
#pragma unroll
    for (int ks = 0; ks < 8; ks++)
        pa[ks] = *(const bf16x8*)&Pl[wave * 16 + lr][ks * 32 + kg * 8];
    f32x4 ov[4] = {};
#pragma unroll
    for (int dt = 0; dt < 4; dt++)
#pragma unroll
        for (int ks = 0; ks < 8; ks++) {
            bf16x8 vb = *(const bf16x8*)&VT[dt * 16 + lr][ks * 32 + kg * 8];
            ov[dt] = __builtin_amdgcn_mfma_f32_16x16x32_bf16(pa[ks], vb, ov[dt], 0, 0, 0);
        }

#pragma unroll
    for (int dt = 0; dt < 4; dt++)
#pragma unroll
        for (int r = 0; r < 4; r++) {
            int n = n0 + wave * 16 + (lane >> 4) * 4 + r;
            if (n < VS) {
                long addr = qmBase + (long)n * DIM + dt * 16 + lr;
                O[addr] = Qm[addr] + ov[dt][r];
            }
        }
}

static inline GJob mkjob(const float* A, int aRows, long aBS, long aOff,
                         const float* W, const float* bias,
                         const float* Add, int addRows, long addBS, long addOff,
                         float* Out, int M, float scale, int relu) {
    GJob j;
    j.A = A; j.W = W; j.bias = bias; j.Add = Add; j.Out = Out;
    j.aBS = aBS; j.aOff = aOff; j.addBS = addBS; j.addOff = addOff;
    j.aRows = aRows; j.addRows = addRows; j.M = M; j.relu = relu;
    j.scale = scale; j.pad0 = j.pad1 = j.pad2 = 0;
    return j;
}

extern "C" void kernel_launch(void* const* d_in, const int* in_sizes, int n_in,
                              void* d_out, int out_size, void* d_ws, size_t ws_size,
                              hipStream_t stream) {
    const float* x     = (const float*)d_in[0];
    const float* Wq    = (const float*)d_in[1];
    const float* Wk    = (const float*)d_in[2];
    const float* Wv    = (const float*)d_in[3];
    const float* Wproj = (const float*)d_in[4];
    const float* bproj = (const float*)d_in[5];
    const float* dw1   = (const float*)d_in[6];
    const float* dw2   = (const float*)d_in[7];
    const float* pw    = (const float*)d_in[8];
    const float* bn1g  = (const float*)d_in[9];
    const float* bn1b  = (const float*)d_in[10];
    const float* bn1m  = (const float*)d_in[11];
    const float* bn1v  = (const float*)d_in[12];
    const float* bn2g  = (const float*)d_in[13];
    const float* bn2b  = (const float*)d_in[14];
    const float* bn2m  = (const float*)d_in[15];
    const float* bn2v  = (const float*)d_in[16];
    const float* mWq   = (const float*)d_in[17];
    const float* mbq   = (const float*)d_in[18];
    const float* mWk   = (const float*)d_in[19];
    const float* mbk   = (const float*)d_in[20];
    const float* mWv   = (const float*)d_in[21];
    const float* mbv   = (const float*)d_in[22];
    const float* mWo   = (const float*)d_in[23];
    const float* mbo   = (const float*)d_in[24];

    float* ws = (float*)d_ws;
    // Overlay (floats):
    //   qs @ 0 (460800) -> m2 -> Km
    //   ks @ 460800 (401408) -> O
    //   vsb @ 862208 (401408) -> O2
    //   P @ 1263616 (1411200) -> [kc @ +0 | Qm @ +460800 | Vm @ +862208]
    float* qs = ws;
    float* ks = ws + 460800;
    float* vsb = ws + 862208;
    float* P  = ws + 1263616;
    float* m2 = ws;
    float* kc = ws + 1263616;
    float* Qm = ws + 1263616 + 460800;
    float* Vm = ws + 1263616 + 460800 + 401408;
    float* Km = ws;
    float* O  = ws + 460800;
    float* O2 = ws + 862208;

    const long xBS = 421L * DIM;
    const long clsOff = 196L * DIM;

    dim3 blk(256);

    // L1: q,k,v projections fused (360 blocks)
    {
        GJobs js;
        js.j[0] = mkjob(x, QL, xBS, clsOff, Wq, nullptr, nullptr, 1, 0, 0, qs, 900, 0.125f, 0);
        js.j[1] = mkjob(x, VS, xBS, 0, Wk, nullptr, nullptr, 1, 0, 0, ks, 784, 1.f, 0);
        js.j[2] = mkjob(x, VS, xBS, 0, Wv, nullptr, nullptr, 1, 0, 0, vsb, 784, 1.f, 0);
        js.j[3] = js.j[0];
        gemm_multi<0><<<dim3(8, 15, 3), blk, 0, stream>>>(js);
    }
    attn1_kernel<<<BATCH * HEADS * QL, blk, 0, stream>>>(qs, ks, P);
    conv_pk_kernel<<<BATCH * 256, blk, 0, stream>>>(P, vsb, dw1, dw2,
                                                    bn1g, bn1b, bn1m, bn1v,
                                                    bn2g, bn2b, bn2m, bn2v, m2);
    // L2: kc = cls_cat + m2 @ pw^T  AND  Qm = x_sem @ mWq^T + mbq   (P dead now)
    {
        GJobs js;
        js.j[0] = mkjob(m2, 900, 0, 0, pw, nullptr, x, QL, xBS, clsOff, kc, 900, 1.f, 0);
        js.j[1] = mkjob(x, VS, xBS, 0, mWq, mbq, nullptr, 1, 0, 0, Qm, 784, 1.f, 0);
        js.j[2] = js.j[3] = js.j[0];
        gemm_multi<1><<<dim3(8, 15, 2), blk, 0, stream>>>(js);
    }
    // L3: Km, Vm off kc
    {
        GJobs js;
        js.j[0] = mkjob(kc, 900, 0, 0, mWk, mbk, nullptr, 1, 0, 0, Km, 900, 1.f, 0);
        js.j[1] = mkjob(kc, 900, 0, 0, mWv, mbv, nullptr, 1, 0, 0, Vm, 900, 1.f, 0);
        js.j[2] = js.j[3] = js.j[0];
        gemm_multi<2><<<dim3(8, 15, 2), blk, 0, stream>>>(js);
    }
    attn2_mfma<<<BATCH * HEADS * 4, blk, 0, stream>>>(Qm, Km, Vm, O);
    // L4: O2 = O + relu(O @ mWo^T + mbo)
    {
        GJobs js;
        js.j[0] = mkjob(O, 784, 0, 0, mWo, mbo, O, 784, 0, 0, O2, 784, 1.f, 1);
        js.j[1] = js.j[2] = js.j[3] = js.j[0];
        gemm_multi<3><<<dim3(8, 13, 1), blk, 0, stream>>>(js);
    }
    // L5: out = O2 @ Wproj^T + bproj
    {
        GJobs js;
        js.j[0] = mkjob(O2, 784, 0, 0, Wproj, bproj, nullptr, 1, 0, 0, (float*)d_out, 784, 1.f, 0);
        js.j[1] = js.j[2] = js.j[3] = js.j[0];
        gemm_multi<4><<<dim3(8, 13, 1), blk, 0, stream>>>(js);
    }
}

// Round 13
// 208.105 us; speedup vs baseline: 1.7512x; 1.0753x over previous
//
#include <hip/hip_runtime.h>
#include <math.h>

#define DIM 512
#define HEADS 8
#define QL 225
#define VS 196
#define BATCH 4
#define EPS_BN 1e-5f

typedef __attribute__((ext_vector_type(8))) short bf16x8;
typedef __attribute__((ext_vector_type(4))) float f32x4;
typedef __attribute__((ext_vector_type(2))) float f32x2;

// ---------------- packed fp32 ops (CDNA VOP3P) ----------------
__device__ __forceinline__ f32x2 pk_fma(f32x2 a, f32x2 b, f32x2 c) {
    f32x2 d;
    asm("v_pk_fma_f32 %0, %1, %2, %3" : "=v"(d) : "v"(a), "v"(b), "v"(c));
    return d;
}
__device__ __forceinline__ f32x2 pk_mul(f32x2 a, f32x2 b) {
    f32x2 d;
    asm("v_pk_mul_f32 %0, %1, %2" : "=v"(d) : "v"(a), "v"(b));
    return d;
}
__device__ __forceinline__ f32x2 pk_add(f32x2 a, f32x2 b) {
    f32x2 d;
    asm("v_pk_add_f32 %0, %1, %2" : "=v"(d) : "v"(a), "v"(b));
    return d;
}
__device__ __forceinline__ f32x2 pk_max0(f32x2 a) {
    f32x2 d;
    d.x = fmaxf(a.x, 0.f); d.y = fmaxf(a.y, 0.f);
    return d;
}

// ---------------- fp32 -> bf16 pack helpers ----------------
__device__ __forceinline__ unsigned cvt_pk_bf16(float lo, float hi) {
    unsigned r;
    asm("v_cvt_pk_bf16_f32 %0, %1, %2" : "=v"(r) : "v"(lo), "v"(hi));
    return r;
}
__device__ __forceinline__ uint4 ld_cvt8(const float* p) {
    float4 x = *(const float4*)p;
    float4 y = *(const float4*)(p + 4);
    uint4 r;
    r.x = cvt_pk_bf16(x.x, x.y);
    r.y = cvt_pk_bf16(x.z, x.w);
    r.z = cvt_pk_bf16(y.x, y.y);
    r.w = cvt_pk_bf16(y.z, y.w);
    return r;
}
// load 8 floats from p (+ optionally p2, summed fp32) then cvt to bf16
__device__ __forceinline__ uint4 ld_cvt8s(const float* p, const float* p2) {
    float4 x = *(const float4*)p;
    float4 y = *(const float4*)(p + 4);
    if (p2) {
        float4 x2 = *(const float4*)p2;
        float4 y2 = *(const float4*)(p2 + 4);
        x.x += x2.x; x.y += x2.y; x.z += x2.z; x.w += x2.w;
        y.x += y2.x; y.y += y2.y; y.z += y2.z; y.w += y2.w;
    }
    uint4 r;
    r.x = cvt_pk_bf16(x.x, x.y);
    r.y = cvt_pk_bf16(x.z, x.w);
    r.z = cvt_pk_bf16(y.x, y.y);
    r.w = cvt_pk_bf16(y.z, y.w);
    return r;
}

// ---------------- multi-job bf16-MFMA GEMM (N=K=512): Out = scale*(A[+A2])@W^T (+bias)(relu)(+Add) ----
struct GJob {
    const float* A; const float* W; const float* bias; const float* Add; float* Out;
    const float* A2lo; const float* A2hi;     // optional second A summed into A (split at a2split rows)
    long aBS, aOff, addBS, addOff;
    int aRows, addRows, M, relu;
    float scale; int a2split; int pad1, pad2;
};
struct GJobs { GJob j[4]; };

template<int LAYER>
__global__ __launch_bounds__(256) void gemm_multi(GJobs jobs) {
    const GJob J = jobs.j[blockIdx.z];
    const int bm = blockIdx.y * 64, bn = blockIdx.x * 64;
    if (bm >= J.M) return;
    __shared__ __align__(16) ushort As[64][72];
    __shared__ __align__(16) ushort Bs[64][72];
    const int tid = threadIdx.x;
    const int srow = tid >> 2, skq = tid & 3;
    const float *ap = nullptr, *ap2 = nullptr;
    {
        int m0 = bm + srow;
        if (m0 < J.M) {
            int bb = m0 / J.aRows; int r = m0 - bb * J.aRows;
            ap = J.A + bb * J.aBS + J.aOff + (long)r * 512 + skq * 16;
            if (J.A2lo) {   // split jobs have aRows == M (bb == 0)
                ap2 = (m0 < J.a2split ? J.A2lo + (long)m0 * 512
                                      : J.A2hi + (long)(m0 - J.a2split) * 512) + skq * 16;
            }
        }
    }
    const float* bp = J.W + (long)(bn + srow) * 512 + skq * 16;

    const int lane = tid & 63, wid = tid >> 6;
    const int wr = wid >> 1, wc = wid & 1;
    const int lr = lane & 15, kg = lane >> 4;

    f32x4 acc[2][2] = {};

    uint4 a01 = {0u,0u,0u,0u}, a23 = {0u,0u,0u,0u};
    if (ap) { a01 = ld_cvt8s(ap, ap2); a23 = ld_cvt8s(ap + 8, ap2 ? ap2 + 8 : nullptr); }
    uint4 b01 = ld_cvt8(bp), b23 = ld_cvt8(bp + 8);

    for (int kt = 0; kt < 512; kt += 64) {
        __syncthreads();
        *(uint4*)&As[srow][skq * 16]     = a01;
        *(uint4*)&As[srow][skq * 16 + 8] = a23;
        *(uint4*)&Bs[srow][skq * 16]     = b01;
        *(uint4*)&Bs[srow][skq * 16 + 8] = b23;
        __syncthreads();
        if (kt + 64 < 512) {
            if (ap) {
                a01 = ld_cvt8s(ap + kt + 64, ap2 ? ap2 + kt + 64 : nullptr);
                a23 = ld_cvt8s(ap + kt + 72, ap2 ? ap2 + kt + 72 : nullptr);
            }
            b01 = ld_cvt8(bp + kt + 64); b23 = ld_cvt8(bp + kt + 72);
        }
        bf16x8 a[2][2], bb[2][2];
#pragma unroll
        for (int i = 0; i < 2; i++)
#pragma unroll
            for (int kf = 0; kf < 2; kf++)
                a[i][kf] = *(const bf16x8*)&As[wr * 32 + i * 16 + lr][kf * 32 + kg * 8];
#pragma unroll
        for (int j = 0; j < 2; j++)
#pragma unroll
            for (int kf = 0; kf < 2; kf++)
                bb[j][kf] = *(const bf16x8*)&Bs[wc * 32 + j * 16 + lr][kf * 32 + kg * 8];
#pragma unroll
        for (int i = 0; i < 2; i++)
#pragma unroll
            for (int j = 0; j < 2; j++) {
                acc[i][j] = __builtin_amdgcn_mfma_f32_16x16x32_bf16(a[i][0], bb[j][0], acc[i][j], 0, 0, 0);
                acc[i][j] = __builtin_amdgcn_mfma_f32_16x16x32_bf16(a[i][1], bb[j][1], acc[i][j], 0, 0, 0);
            }
    }

#pragma unroll
    for (int i = 0; i < 2; i++) {
#pragma unroll
        for (int r = 0; r < 4; r++) {
            int m = bm + wr * 32 + i * 16 + kg * 4 + r;
            if (m >= J.M) continue;
            const float* addrow = nullptr;
            if (J.Add) {
                int bb2 = m / J.addRows; int rr = m - bb2 * J.addRows;
                addrow = J.Add + bb2 * J.addBS + J.addOff + (long)rr * 512;
            }
            float* orow = J.Out + (long)m * 512;
#pragma unroll
            for (int j = 0; j < 2; j++) {
                int n = bn + wc * 32 + j * 16 + lr;
                float v = acc[i][j][r] * J.scale;
                if (J.bias) v += J.bias[n];
                if (J.relu) v = fmaxf(v, 0.f);
                if (addrow) v += addrow[n];
                orow[n] = v;
            }
        }
    }
}

// ---------------- attention 1 via MFMA: P^T[n][q] = softmax_n(q·k) ----
// Block = (b, h, q-tile of 64). A-frags = K rows (n -> C rows), B-frags = Q rows
// (q -> C cols) => C = S^T directly. Softmax over n: 52 in-lane + shfl_xor(16,32).
__global__ __launch_bounds__(256) void attn1_mfma(const float* __restrict__ qs,
                                                  const float* __restrict__ ks,
                                                  float* __restrict__ P) {
    int bid = blockIdx.x;          // 128 = b(4) x h(8) x qt(4)
    int qt = bid & 3;
    int h = (bid >> 2) & 7;
    int b = bid >> 5;
    int tid = threadIdx.x;
    int wave = tid >> 6, lane = tid & 63;
    int lr = lane & 15, kg = lane >> 4;
    __shared__ __align__(16) ushort Kb[208][72];
    __shared__ __align__(16) ushort Qb[64][72];
    const long qBase = ((long)(b * QL)) * DIM + h * 64;
    const long kBase = ((long)(b * VS)) * DIM + h * 64;
    {   // stage Q tile (zero rows past QL)
        int r = tid >> 2, c0 = (tid & 3) * 16;
        int q = qt * 64 + r;
        uint4 lo = {0u,0u,0u,0u}, hi = {0u,0u,0u,0u};
        if (q < QL) {
            const float* s = qs + qBase + (long)q * DIM + c0;
            lo = ld_cvt8(s); hi = ld_cvt8(s + 8);
        }
        *(uint4*)&Qb[r][c0] = lo; *(uint4*)&Qb[r][c0 + 8] = hi;
    }
    {   // stage K rows 0..207 (zero past VS)
        int c0 = (tid & 3) * 16;
#pragma unroll
        for (int i = 0; i < 4; i++) {
            int r = (tid >> 2) + 64 * i;
            if (r < 208) {
                uint4 lo = {0u,0u,0u,0u}, hi = {0u,0u,0u,0u};
                if (r < VS) {
                    const float* s = ks + kBase + (long)r * DIM + c0;
                    lo = ld_cvt8(s); hi = ld_cvt8(s + 8);
                }
                *(uint4*)&Kb[r][c0] = lo; *(uint4*)&Kb[r][c0 + 8] = hi;
            }
        }
    }
    __syncthreads();

    bf16x8 bq0 = *(const bf16x8*)&Qb[wave * 16 + lr][kg * 8];
    bf16x8 bq1 = *(const bf16x8*)&Qb[wave * 16 + lr][32 + kg * 8];
    f32x4 sc[13];
#pragma unroll
    for (int ct = 0; ct < 13; ct++) {
        bf16x8 a0 = *(const bf16x8*)&Kb[ct * 16 + lr][kg * 8];
        bf16x8 a1 = *(const bf16x8*)&Kb[ct * 16 + lr][32 + kg * 8];
        f32x4 z = {0.f, 0.f, 0.f, 0.f};
        z = __builtin_amdgcn_mfma_f32_16x16x32_bf16(a0, bq0, z, 0, 0, 0);
        z = __builtin_amdgcn_mfma_f32_16x16x32_bf16(a1, bq1, z, 0, 0, 0);
        sc[ct] = z;
    }
    // mask n >= VS (tile 12, kg > 0), then softmax over n per q-column
    float m = -1e30f;
#pragma unroll
    for (int ct = 0; ct < 13; ct++)
#pragma unroll
        for (int r = 0; r < 4; r++) {
            if (ct == 12 && kg > 0) sc[ct][r] = -1e30f;
            m = fmaxf(m, sc[ct][r]);
        }
    m = fmaxf(m, __shfl_xor(m, 16, 64));
    m = fmaxf(m, __shfl_xor(m, 32, 64));
    float s = 0.f;
#pragma unroll
    for (int ct = 0; ct < 13; ct++)
#pragma unroll
        for (int r = 0; r < 4; r++) {
            float e = expf(sc[ct][r] - m);
            sc[ct][r] = e;
            s += e;
        }
    s += __shfl_xor(s, 16, 64);
    s += __shfl_xor(s, 32, 64);
    float inv = 1.f / s;
    int q = qt * 64 + wave * 16 + lr;
    if (q < QL) {
        float* Pp = P + ((long)(b * HEADS + h)) * VS * QL + q;
#pragma unroll
        for (int ct = 0; ct < 13; ct++)
#pragma unroll
            for (int r = 0; r < 4; r++) {
                int n = ct * 16 + kg * 4 + r;
                if (n < VS) Pp[(long)n * QL] = sc[ct][r] * inv;
            }
    }
}

// ---------------- fused conv v7: packed channel-pair + producer partials + 2-way n-split ----
__device__ __forceinline__ float ldP(const float* Pp, int N, int q, bool qload) {
    float ps = 0.f;
    if (qload && N < VS) ps = Pp[(long)N * QL + q];
    return ps;
}

#define CSTEP7(N, PS, TAw,TAm2, TBw,TBm1, UAw,UAm2, UBw,UBm1)                      \
{                                                                                  \
    f32x2 vn = vcol2[(N)];                                                         \
    f32x2 pv; pv.x = (PS) * vn.x; pv.y = (PS) * vn.y;                              \
    f32x2 hm, hp;                                                                  \
    hm.x = __shfl_up(pv.x, 1, 64);   hm.y = __shfl_up(pv.y, 1, 64);                \
    hp.x = __shfl_down(pv.x, 1, 64); hp.y = __shfl_down(pv.y, 1, 64);              \
    f32x2 g = z2;                                                                  \
    if (gok && (N) >= 1 && (N) <= VS) {                                            \
        f32x2 tC = pk_fma(hp, w1p[8], pk_fma(pv, w1p[7], pk_mul(hm, w1p[6])));     \
        f32x2 sg = pk_add(tC, pk_add(TBm1, pk_add(TAm2, b1v2)));                   \
        g = pk_max0(sg);                                                           \
    }                                                                              \
    TAw = pk_fma(hp, w1p[2], pk_fma(pv, w1p[1], pk_mul(hm, w1p[0])));              \
    TBw = pk_fma(hp, w1p[5], pk_fma(pv, w1p[4], pk_mul(hm, w1p[3])));              \
    f32x2 gm, gp;                                                                  \
    gm.x = __shfl_up(g.x, 1, 64);   gm.y = __shfl_up(g.y, 1, 64);                  \
    gp.x = __shfl_down(g.x, 1, 64); gp.y = __shfl_down(g.y, 1, 64);                \
    if ((N) >= alo && (N) <= ahi) {                                                \
        f32x2 uC = pk_fma(gp, w2p[8], pk_fma(g, w2p[7], pk_mul(gm, w2p[6])));      \
        f32x2 s2 = pk_add(uC, pk_add(UBm1, pk_add(UAm2, b2v2)));                   \
        csum = pk_add(csum, pk_max0(s2));                                          \
    }                                                                              \
    UAw = pk_fma(gp, w2p[2], pk_fma(g, w2p[1], pk_mul(gm, w2p[0])));               \
    UBw = pk_fma(gp, w2p[5], pk_fma(g, w2p[4], pk_mul(gm, w2p[3])));               \
}

__global__ __launch_bounds__(256) void conv_pk_kernel(
    const float* __restrict__ P, const float* __restrict__ vs,
    const float* __restrict__ dw1, const float* __restrict__ dw2,
    const float* __restrict__ bn1g, const float* __restrict__ bn1b,
    const float* __restrict__ bn1m, const float* __restrict__ bn1v,
    const float* __restrict__ bn2g, const float* __restrict__ bn2b,
    const float* __restrict__ bn2m, const float* __restrict__ bn2v,
    float* __restrict__ m2a, float* __restrict__ m2b1, float* __restrict__ m2b2) {
    int bc = blockIdx.x;            // 2048 = b(4) x cpair(256) x half(2)
    int half = bc & 1;
    int c0 = ((bc >> 1) & 255) * 2;
    int b = bc >> 9;
    int h = c0 >> 6;
    // half 0: stream N=0..101, accumulate h2 rows 0..97  (N in [2,99])
    // half 1: stream N=96..197, accumulate h2 rows 98..195 (N in [100,197]);
    //   4-row warm-up: garbage partials from N=96..99 expire before N=100.
    const int no  = half ? 96 : 0;
    const int alo = half ? 100 : 2;
    const int ahi = half ? 197 : 99;
    int tid = threadIdx.x;
    int wave = tid >> 6, lane = tid & 63;
    int q = wave * 60 + lane - 2;
    bool qload = (q >= 0 && q < QL);
    bool gok = (lane >= 1 && lane <= 62 && q >= 0 && q < QL);
    bool outok = (lane >= 2 && lane <= 61 && q < QL);
    __shared__ __align__(8) f32x2 vcol2[200];   // zero-padded past VS
    if (tid < 200) {
        f32x2 t = {0.f, 0.f};
        if (tid < VS) {
            const float* vp = vs + ((long)(b * VS + tid)) * DIM + c0;
            t.x = vp[0]; t.y = vp[1];
        }
        vcol2[tid] = t;
    }
    float s1x = bn1g[c0]     * rsqrtf(bn1v[c0]     + EPS_BN);
    float s1y = bn1g[c0 + 1] * rsqrtf(bn1v[c0 + 1] + EPS_BN);
    float s2x = bn2g[c0]     * rsqrtf(bn2v[c0]     + EPS_BN);
    float s2y = bn2g[c0 + 1] * rsqrtf(bn2v[c0 + 1] + EPS_BN);
    f32x2 b1v2; b1v2.x = bn1b[c0] - bn1m[c0] * s1x; b1v2.y = bn1b[c0 + 1] - bn1m[c0 + 1] * s1y;
    f32x2 b2v2; b2v2.x = bn2b[c0] - bn2m[c0] * s2x; b2v2.y = bn2b[c0 + 1] - bn2m[c0 + 1] * s2y;
    f32x2 w1p[9], w2p[9];
#pragma unroll
    for (int i = 0; i < 9; i++) {
        w1p[i].x = dw1[c0 * 9 + i] * s1x;       w1p[i].y = dw1[(c0 + 1) * 9 + i] * s1y;
        w2p[i].x = dw2[c0 * 9 + i] * s2x;       w2p[i].y = dw2[(c0 + 1) * 9 + i] * s2y;
    }
    const float* Pp = P + ((long)(b * HEADS + h)) * VS * QL;
    __syncthreads();
    const f32x2 z2 = {0.f, 0.f};
    f32x2 tAa = z2, tAb = z2, tAc = z2, tBa = z2, tBb = z2, tBc = z2;
    f32x2 uAa = z2, uAb = z2, uAc = z2, uBa = z2, uBb = z2, uBc = z2;
    f32x2 csum = z2;
    float ps0 = ldP(Pp, no + 0, q, qload);
    float ps1 = ldP(Pp, no + 1, q, qload);
    float ps2 = ldP(Pp, no + 2, q, qload);
    for (int s = 0; s < 102; s += 3) {
        int N0 = no + s;
        float pn0 = ldP(Pp, N0 + 3, q, qload);
        float pn1 = ldP(Pp, N0 + 4, q, qload);
        float pn2 = ldP(Pp, N0 + 5, q, qload);
        CSTEP7(N0,     ps0, tAa,tAb, tBa,tBc, uAa,uAb, uBa,uBc)
        CSTEP7(N0 + 1, ps1, tAb,tAc, tBb,tBa, uAb,uAc, uBb,uBa)
        CSTEP7(N0 + 2, ps2, tAc,tAa, tBc,tBb, uAc,uAa, uBc,uBb)
        ps0 = pn0; ps1 = pn1; ps2 = pn2;
    }
    if (outok) {
        const float inv = 1.f / (float)VS;
        f32x2 o; o.x = csum.x * inv; o.y = csum.y * inv;
        int row = b * QL + q;
        if (!half) {
            *(f32x2*)&m2a[(long)row * 512 + c0] = o;
        } else {
            float* dst = (row < 784) ? (m2b1 + (long)row * 512) : (m2b2 + (long)(row - 784) * 512);
            *(f32x2*)&dst[c0] = o;
        }
    }
}

// ---------------- attention 2 via MFMA (R10-proven) ----------------
__global__ __launch_bounds__(256) void attn2_mfma(const float* __restrict__ Qm,
                                                  const float* __restrict__ Km,
                                                  const float* __restrict__ Vm,
                                                  float* __restrict__ O) {
    int bid = blockIdx.x;          // 128 = b(4) x h(8) x nq(4)
    int nq = bid & 3;
    int h = (bid >> 2) & 7;
    int b = bid >> 5;
    int n0 = nq * 64;
    int tid = threadIdx.x;
    int wave = tid >> 6, lane = tid & 63;
    int lr = lane & 15, kg = lane >> 4;

    __shared__ __align__(16) char smem[77568];
    ushort (*VT)[264] = (ushort(*)[264])smem;            // [64][264]  VT[d][q]
    ushort (*Qb)[72]  = (ushort(*)[72])(smem + 33792);   // [64][72]
    ushort (*Kb)[72]  = (ushort(*)[72])(smem + 43008);   // [240][72]
    ushort (*Pl)[264] = (ushort(*)[264])(smem + 33792);  // [64][264] aliases Qb/Kb

    const long qmBase = ((long)(b * VS)) * DIM + h * 64;
    const long kmBase = ((long)(b * QL)) * DIM + h * 64;

    {
        int r = tid >> 2, c0 = (tid & 3) * 16;
        int n = min(n0 + r, VS - 1);
        const float* src = Qm + qmBase + (long)n * DIM + c0;
        *(uint4*)&Qb[r][c0]     = ld_cvt8(src);
        *(uint4*)&Qb[r][c0 + 8] = ld_cvt8(src + 8);
    }
    {
        int c0 = (tid & 3) * 16;
#pragma unroll
        for (int i = 0; i < 4; i++) {
            int r = (tid >> 2) + 64 * i;
            if (r < 240) {
                uint4 lo = {0u,0u,0u,0u}, hi = {0u,0u,0u,0u};
                if (r < QL) {
                    const float* src = Km + kmBase + (long)r * DIM + c0;
                    lo = ld_cvt8(src); hi = ld_cvt8(src + 8);
                }
                *(uint4*)&Kb[r][c0]     = lo;
                *(uint4*)&Kb[r][c0 + 8] = hi;
            }
        }
    }
    {
        int c0 = (tid & 3) * 16;
#pragma unroll
        for (int i = 0; i < 4; i++) {
            int qq = (tid >> 2) + 64 * i;
            if (qq < 240) {
                ushort u[16];
                if (qq < QL) {
                    const float* src = Vm + kmBase + (long)qq * DIM + c0;
                    *(uint4*)&u[0] = ld_cvt8(src);
                    *(uint4*)&u[8] = ld_cvt8(src + 8);
                } else {
#pragma unroll
                    for (int j = 0; j < 16; j++) u[j] = 0;
                }
#pragma unroll
                for (int j = 0; j < 16; j++) VT[c0 + j][qq] = u[j];
            }
        }
        int d = tid >> 2, qz = 240 + (tid & 3) * 4;
#pragma unroll
        for (int j = 0; j < 4; j++) VT[d][qz + j] = 0;
    }
    __syncthreads();

    bf16x8 a0 = *(const bf16x8*)&Qb[wave * 16 + lr][kg * 8];
    bf16x8 a1 = *(const bf16x8*)&Qb[wave * 16 + lr][32 + kg * 8];
    f32x4 sc[15];
#pragma unroll
    for (int ct = 0; ct < 15; ct++) {
        bf16x8 b0 = *(const bf16x8*)&Kb[ct * 16 + lr][kg * 8];
        bf16x8 b1 = *(const bf16x8*)&Kb[ct * 16 + lr][32 + kg * 8];
        f32x4 z = {0.f, 0.f, 0.f, 0.f};
        z = __builtin_amdgcn_mfma_f32_16x16x32_bf16(a0, b0, z, 0, 0, 0);
        z = __builtin_amdgcn_mfma_f32_16x16x32_bf16(a1, b1, z, 0, 0, 0);
        sc[ct] = z;
    }
    __syncthreads();

    const float scl = 0.044194173824159216f;
    float pinv[4];
#pragma unroll
    for (int r = 0; r < 4; r++) {
        float m = -1e30f;
#pragma unroll
        for (int ct = 0; ct < 15; ct++) {
            float v = sc[ct][r] * scl;
            if (ct * 16 + lr >= QL) v = -1e30f;
            sc[ct][r] = v;
            m = fmaxf(m, v);
        }
#pragma unroll
        for (int o = 1; o < 16; o <<= 1) m = fmaxf(m, __shfl_xor(m, o, 64));
        float s = 0.f;
#pragma unroll
        for (int ct = 0; ct < 15; ct++) {
            float e = expf(sc[ct][r] - m);
            sc[ct][r] = e;
            s += e;
        }
#pragma unroll
        for (int o = 1; o < 16; o <<= 1) s += __shfl_xor(s, o, 64);
        pinv[r] = 1.f / s;
    }
#pragma unroll
    for (int r = 0; r < 4; r++) {
        int row = wave * 16 + (lane >> 4) * 4 + r;
#pragma unroll
        for (int ct = 0; ct < 15; ct++) {
            float p = sc[ct][r] * pinv[r];
            Pl[row][ct * 16 + lr] = (ushort)(cvt_pk_bf16(p, p) & 0xffffu);
        }
        Pl[row][240 + lr] = 0;
    }
    __syncthreads();

    bf16x8 pa[8];
#pragma unroll
    for (int ks = 0; ks < 8; ks++)
        pa[ks] = *(const bf16x8*)&Pl[wave * 16 + lr][ks * 32 + kg * 8];
    f32x4 ov[4] = {};
#pragma unroll
    for (int dt = 0; dt < 4; dt++)
#pragma unroll
        for (int ks = 0; ks < 8; ks++) {
            bf16x8 vb = *(const bf16x8*)&VT[dt * 16 + lr][ks * 32 + kg * 8];
            ov[dt] = __builtin_amdgcn_mfma_f32_16x16x32_bf16(pa[ks], vb, ov[dt], 0, 0, 0);
        }

#pragma unroll
    for (int dt = 0; dt < 4; dt++)
#pragma unroll
        for (int r = 0; r < 4; r++) {
            int n = n0 + wave * 16 + (lane >> 4) * 4 + r;
            if (n < VS) {
                long addr = qmBase + (long)n * DIM + dt * 16 + lr;
                O[addr] = Qm[addr] + ov[dt][r];
            }
        }
}

static inline GJob mkjob(const float* A, int aRows, long aBS, long aOff,
                         const float* W, const float* bias,
                         const float* Add, int addRows, long addBS, long addOff,
                         float* Out, int M, float scale, int relu,
                         const float* A2lo = nullptr, const float* A2hi = nullptr,
                         int a2split = 0) {
    GJob j;
    j.A = A; j.W = W; j.bias = bias; j.Add = Add; j.Out = Out;
    j.A2lo = A2lo; j.A2hi = A2hi;
    j.aBS = aBS; j.aOff = aOff; j.addBS = addBS; j.addOff = addOff;
    j.aRows = aRows; j.addRows = addRows; j.M = M; j.relu = relu;
    j.scale = scale; j.a2split = a2split; j.pad1 = j.pad2 = 0;
    return j;
}

extern "C" void kernel_launch(void* const* d_in, const int* in_sizes, int n_in,
                              void* d_out, int out_size, void* d_ws, size_t ws_size,
                              hipStream_t stream) {
    const float* x     = (const float*)d_in[0];
    const float* Wq    = (const float*)d_in[1];
    const float* Wk    = (const float*)d_in[2];
    const float* Wv    = (const float*)d_in[3];
    const float* Wproj = (const float*)d_in[4];
    const float* bproj = (const float*)d_in[5];
    const float* dw1   = (const float*)d_in[6];
    const float* dw2   = (const float*)d_in[7];
    const float* pw    = (const float*)d_in[8];
    const float* bn1g  = (const float*)d_in[9];
    const float* bn1b  = (const float*)d_in[10];
    const float* bn1m  = (const float*)d_in[11];
    const float* bn1v  = (const float*)d_in[12];
    const float* bn2g  = (const float*)d_in[13];
    const float* bn2b  = (const float*)d_in[14];
    const float* bn2m  = (const float*)d_in[15];
    const float* bn2v  = (const float*)d_in[16];
    const float* mWq   = (const float*)d_in[17];
    const float* mbq   = (const float*)d_in[18];
    const float* mWk   = (const float*)d_in[19];
    const float* mbk   = (const float*)d_in[20];
    const float* mWv   = (const float*)d_in[21];
    const float* mbv   = (const float*)d_in[22];
    const float* mWo   = (const float*)d_in[23];
    const float* mbo   = (const float*)d_in[24];

    float* ws = (float*)d_ws;
    // Overlay (floats):
    //   qs @ 0 (460800) -> m2a -> Km
    //   ks @ 460800 (401408) -> m2b1 -> O
    //   vsb @ 862208 (401408) -> O2
    //   P @ 1263616 (1411200) -> [kc @ +0 | Qm @ +460800 | Vm @ +862208]
    //   m2b2 = d_out scratch (rows 784..899 of half-1 partials; consumed by L2, overwritten by L5)
    float* qs = ws;
    float* ks = ws + 460800;
    float* vsb = ws + 862208;
    float* P  = ws + 1263616;
    float* m2a = ws;            // reuses qs
    float* m2b1 = ws + 460800;  // reuses ks
    float* m2b2 = (float*)d_out;
    float* kc = ws + 1263616;
    float* Qm = ws + 1263616 + 460800;
    float* Vm = ws + 1263616 + 460800 + 401408;
    float* Km = ws;
    float* O  = ws + 460800;
    float* O2 = ws + 862208;

    const long xBS = 421L * DIM;
    const long clsOff = 196L * DIM;

    dim3 blk(256);

    // L1: q,k,v projections fused (360 blocks)
    {
        GJobs js;
        js.j[0] = mkjob(x, QL, xBS, clsOff, Wq, nullptr, nullptr, 1, 0, 0, qs, 900, 0.125f, 0);
        js.j[1] = mkjob(x, VS, xBS, 0, Wk, nullptr, nullptr, 1, 0, 0, ks, 784, 1.f, 0);
        js.j[2] = mkjob(x, VS, xBS, 0, Wv, nullptr, nullptr, 1, 0, 0, vsb, 784, 1.f, 0);
        js.j[3] = js.j[0];
        gemm_multi<0><<<dim3(8, 15, 3), blk, 0, stream>>>(js);
    }
    attn1_mfma<<<BATCH * HEADS * 4, blk, 0, stream>>>(qs, ks, P);
    conv_pk_kernel<<<2048, blk, 0, stream>>>(P, vsb, dw1, dw2,
                                             bn1g, bn1b, bn1m, bn1v,
                                             bn2g, bn2b, bn2m, bn2v, m2a, m2b1, m2b2);
    // L2: kc = cls_cat + (m2a+m2b) @ pw^T  AND  Qm = x_sem @ mWq^T + mbq
    {
        GJobs js;
        js.j[0] = mkjob(m2a, 900, 0, 0, pw, nullptr, x, QL, xBS, clsOff, kc, 900, 1.f, 0,
                        m2b1, m2b2, 784);
        js.j[1] = mkjob(x, VS, xBS, 0, mWq, mbq, nullptr, 1, 0, 0, Qm, 784, 1.f, 0);
        js.j[2] = js.j[3] = js.j[0];
        gemm_multi<1><<<dim3(8, 15, 2), blk, 0, stream>>>(js);
    }
    // L3: Km, Vm off kc
    {
        GJobs js;
        js.j[0] = mkjob(kc, 900, 0, 0, mWk, mbk, nullptr, 1, 0, 0, Km, 900, 1.f, 0);
        js.j[1] = mkjob(kc, 900, 0, 0, mWv, mbv, nullptr, 1, 0, 0, Vm, 900, 1.f, 0);
        js.j[2] = js.j[3] = js.j[0];
        gemm_multi<2><<<dim3(8, 15, 2), blk, 0, stream>>>(js);
    }
    attn2_mfma<<<BATCH * HEADS * 4, blk, 0, stream>>>(Qm, Km, Vm, O);
    // L4: O2 = O + relu(O @ mWo^T + mbo)
    {
        GJobs js;
        js.j[0] = mkjob(O, 784, 0, 0, mWo, mbo, O, 784, 0, 0, O2, 784, 1.f, 1);
        js.j[1] = js.j[2] = js.j[3] = js.j[0];
        gemm_multi<3><<<dim3(8, 13, 1), blk, 0, stream>>>(js);
    }
    // L5: out = O2 @ Wproj^T + bproj
    {
        GJobs js;
        js.j[0] = mkjob(O2, 784, 0, 0, Wproj, bproj, nullptr, 1, 0, 0, (float*)d_out, 784, 1.f, 0);
        js.j[1] = js.j[2] = js.j[3] = js.j[0];
        gemm_multi<4><<<dim3(8, 13, 1), blk, 0, stream>>>(js);
    }
}

// Round 14
// 207.193 us; speedup vs baseline: 1.7589x; 1.0044x over previous
//
#include <hip/hip_runtime.h>
#include <math.h>

#define DIM 512
#define HEADS 8
#define QL 225
#define VS 196
#define BATCH 4
#define EPS_BN 1e-5f

typedef __attribute__((ext_vector_type(8))) short bf16x8;
typedef __attribute__((ext_vector_type(4))) float f32x4;
typedef __attribute__((ext_vector_type(2))) float f32x2;

// ---------------- packed fp32 ops (CDNA VOP3P) ----------------
__device__ __forceinline__ f32x2 pk_fma(f32x2 a, f32x2 b, f32x2 c) {
    f32x2 d;
    asm("v_pk_fma_f32 %0, %1, %2, %3" : "=v"(d) : "v"(a), "v"(b), "v"(c));
    return d;
}
__device__ __forceinline__ f32x2 pk_mul(f32x2 a, f32x2 b) {
    f32x2 d;
    asm("v_pk_mul_f32 %0, %1, %2" : "=v"(d) : "v"(a), "v"(b));
    return d;
}
__device__ __forceinline__ f32x2 pk_add(f32x2 a, f32x2 b) {
    f32x2 d;
    asm("v_pk_add_f32 %0, %1, %2" : "=v"(d) : "v"(a), "v"(b));
    return d;
}
__device__ __forceinline__ f32x2 pk_max0(f32x2 a) {
    f32x2 d;
    d.x = fmaxf(a.x, 0.f); d.y = fmaxf(a.y, 0.f);
    return d;
}
// raw cross-lane pull (index hoisted by caller; edge lanes read garbage -- harmless by design)
__device__ __forceinline__ float bperm(int idx, float v) {
    return __int_as_float(__builtin_amdgcn_ds_bpermute(idx, __float_as_int(v)));
}

// ---------------- fp32 -> bf16 pack helpers ----------------
__device__ __forceinline__ unsigned cvt_pk_bf16(float lo, float hi) {
    unsigned r;
    asm("v_cvt_pk_bf16_f32 %0, %1, %2" : "=v"(r) : "v"(lo), "v"(hi));
    return r;
}
__device__ __forceinline__ uint4 ld_cvt8(const float* p) {
    float4 x = *(const float4*)p;
    float4 y = *(const float4*)(p + 4);
    uint4 r;
    r.x = cvt_pk_bf16(x.x, x.y);
    r.y = cvt_pk_bf16(x.z, x.w);
    r.z = cvt_pk_bf16(y.x, y.y);
    r.w = cvt_pk_bf16(y.z, y.w);
    return r;
}
__device__ __forceinline__ uint4 ld_cvt8s(const float* p, const float* p2) {
    float4 x = *(const float4*)p;
    float4 y = *(const float4*)(p + 4);
    if (p2) {
        float4 x2 = *(const float4*)p2;
        float4 y2 = *(const float4*)(p2 + 4);
        x.x += x2.x; x.y += x2.y; x.z += x2.z; x.w += x2.w;
        y.x += y2.x; y.y += y2.y; y.z += y2.z; y.w += y2.w;
    }
    uint4 r;
    r.x = cvt_pk_bf16(x.x, x.y);
    r.y = cvt_pk_bf16(x.z, x.w);
    r.z = cvt_pk_bf16(y.x, y.y);
    r.w = cvt_pk_bf16(y.z, y.w);
    return r;
}

// ---------------- multi-job bf16-MFMA GEMM (N=K=512): Out = scale*(A[+A2])@W^T (+bias)(relu)(+Add) ----
struct GJob {
    const float* A; const float* W; const float* bias; const float* Add; float* Out;
    const float* A2lo; const float* A2hi;
    long aBS, aOff, addBS, addOff;
    int aRows, addRows, M, relu;
    float scale; int a2split; int pad1, pad2;
};
struct GJobs { GJob j[4]; };

template<int LAYER>
__global__ __launch_bounds__(256) void gemm_multi(GJobs jobs) {
    const GJob J = jobs.j[blockIdx.z];
    const int bm = blockIdx.y * 64, bn = blockIdx.x * 64;
    if (bm >= J.M) return;
    __shared__ __align__(16) ushort As[64][72];
    __shared__ __align__(16) ushort Bs[64][72];
    const int tid = threadIdx.x;
    const int srow = tid >> 2, skq = tid & 3;
    const float *ap = nullptr, *ap2 = nullptr;
    {
        int m0 = bm + srow;
        if (m0 < J.M) {
            int bb = m0 / J.aRows; int r = m0 - bb * J.aRows;
            ap = J.A + bb * J.aBS + J.aOff + (long)r * 512 + skq * 16;
            if (J.A2lo) {
                ap2 = (m0 < J.a2split ? J.A2lo + (long)m0 * 512
                                      : J.A2hi + (long)(m0 - J.a2split) * 512) + skq * 16;
            }
        }
    }
    const float* bp = J.W + (long)(bn + srow) * 512 + skq * 16;

    const int lane = tid & 63, wid = tid >> 6;
    const int wr = wid >> 1, wc = wid & 1;
    const int lr = lane & 15, kg = lane >> 4;

    f32x4 acc[2][2] = {};

    uint4 a01 = {0u,0u,0u,0u}, a23 = {0u,0u,0u,0u};
    if (ap) { a01 = ld_cvt8s(ap, ap2); a23 = ld_cvt8s(ap + 8, ap2 ? ap2 + 8 : nullptr); }
    uint4 b01 = ld_cvt8(bp), b23 = ld_cvt8(bp + 8);

    for (int kt = 0; kt < 512; kt += 64) {
        __syncthreads();
        *(uint4*)&As[srow][skq * 16]     = a01;
        *(uint4*)&As[srow][skq * 16 + 8] = a23;
        *(uint4*)&Bs[srow][skq * 16]     = b01;
        *(uint4*)&Bs[srow][skq * 16 + 8] = b23;
        __syncthreads();
        if (kt + 64 < 512) {
            if (ap) {
                a01 = ld_cvt8s(ap + kt + 64, ap2 ? ap2 + kt + 64 : nullptr);
                a23 = ld_cvt8s(ap + kt + 72, ap2 ? ap2 + kt + 72 : nullptr);
            }
            b01 = ld_cvt8(bp + kt + 64); b23 = ld_cvt8(bp + kt + 72);
        }
        bf16x8 a[2][2], bb[2][2];
#pragma unroll
        for (int i = 0; i < 2; i++)
#pragma unroll
            for (int kf = 0; kf < 2; kf++)
                a[i][kf] = *(const bf16x8*)&As[wr * 32 + i * 16 + lr][kf * 32 + kg * 8];
#pragma unroll
        for (int j = 0; j < 2; j++)
#pragma unroll
            for (int kf = 0; kf < 2; kf++)
                bb[j][kf] = *(const bf16x8*)&Bs[wc * 32 + j * 16 + lr][kf * 32 + kg * 8];
#pragma unroll
        for (int i = 0; i < 2; i++)
#pragma unroll
            for (int j = 0; j < 2; j++) {
                acc[i][j] = __builtin_amdgcn_mfma_f32_16x16x32_bf16(a[i][0], bb[j][0], acc[i][j], 0, 0, 0);
                acc[i][j] = __builtin_amdgcn_mfma_f32_16x16x32_bf16(a[i][1], bb[j][1], acc[i][j], 0, 0, 0);
            }
    }

#pragma unroll
    for (int i = 0; i < 2; i++) {
#pragma unroll
        for (int r = 0; r < 4; r++) {
            int m = bm + wr * 32 + i * 16 + kg * 4 + r;
            if (m >= J.M) continue;
            const float* addrow = nullptr;
            if (J.Add) {
                int bb2 = m / J.addRows; int rr = m - bb2 * J.addRows;
                addrow = J.Add + bb2 * J.addBS + J.addOff + (long)rr * 512;
            }
            float* orow = J.Out + (long)m * 512;
#pragma unroll
            for (int j = 0; j < 2; j++) {
                int n = bn + wc * 32 + j * 16 + lr;
                float v = acc[i][j][r] * J.scale;
                if (J.bias) v += J.bias[n];
                if (J.relu) v = fmaxf(v, 0.f);
                if (addrow) v += addrow[n];
                orow[n] = v;
            }
        }
    }
}

// ---------------- attention 1 via MFMA (R13-proven): P^T[n][q] = softmax_n(q·k) ----
__global__ __launch_bounds__(256) void attn1_mfma(const float* __restrict__ qs,
                                                  const float* __restrict__ ks,
                                                  float* __restrict__ P) {
    int bid = blockIdx.x;          // 128 = b(4) x h(8) x qt(4)
    int qt = bid & 3;
    int h = (bid >> 2) & 7;
    int b = bid >> 5;
    int tid = threadIdx.x;
    int wave = tid >> 6, lane = tid & 63;
    int lr = lane & 15, kg = lane >> 4;
    __shared__ __align__(16) ushort Kb[208][72];
    __shared__ __align__(16) ushort Qb[64][72];
    const long qBase = ((long)(b * QL)) * DIM + h * 64;
    const long kBase = ((long)(b * VS)) * DIM + h * 64;
    {
        int r = tid >> 2, c0 = (tid & 3) * 16;
        int q = qt * 64 + r;
        uint4 lo = {0u,0u,0u,0u}, hi = {0u,0u,0u,0u};
        if (q < QL) {
            const float* s = qs + qBase + (long)q * DIM + c0;
            lo = ld_cvt8(s); hi = ld_cvt8(s + 8);
        }
        *(uint4*)&Qb[r][c0] = lo; *(uint4*)&Qb[r][c0 + 8] = hi;
    }
    {
        int c0 = (tid & 3) * 16;
#pragma unroll
        for (int i = 0; i < 4; i++) {
            int r = (tid >> 2) + 64 * i;
            if (r < 208) {
                uint4 lo = {0u,0u,0u,0u}, hi = {0u,0u,0u,0u};
                if (r < VS) {
                    const float* s = ks + kBase + (long)r * DIM + c0;
                    lo = ld_cvt8(s); hi = ld_cvt8(s + 8);
                }
                *(uint4*)&Kb[r][c0] = lo; *(uint4*)&Kb[r][c0 + 8] = hi;
            }
        }
    }
    __syncthreads();

    bf16x8 bq0 = *(const bf16x8*)&Qb[wave * 16 + lr][kg * 8];
    bf16x8 bq1 = *(const bf16x8*)&Qb[wave * 16 + lr][32 + kg * 8];
    f32x4 sc[13];
#pragma unroll
    for (int ct = 0; ct < 13; ct++) {
        bf16x8 a0 = *(const bf16x8*)&Kb[ct * 16 + lr][kg * 8];
        bf16x8 a1 = *(const bf16x8*)&Kb[ct * 16 + lr][32 + kg * 8];
        f32x4 z = {0.f, 0.f, 0.f, 0.f};
        z = __builtin_amdgcn_mfma_f32_16x16x32_bf16(a0, bq0, z, 0, 0, 0);
        z = __builtin_amdgcn_mfma_f32_16x16x32_bf16(a1, bq1, z, 0, 0, 0);
        sc[ct] = z;
    }
    float m = -1e30f;
#pragma unroll
    for (int ct = 0; ct < 13; ct++)
#pragma unroll
        for (int r = 0; r < 4; r++) {
            if (ct == 12 && kg > 0) sc[ct][r] = -1e30f;
            m = fmaxf(m, sc[ct][r]);
        }
    m = fmaxf(m, __shfl_xor(m, 16, 64));
    m = fmaxf(m, __shfl_xor(m, 32, 64));
    float s = 0.f;
#pragma unroll
    for (int ct = 0; ct < 13; ct++)
#pragma unroll
        for (int r = 0; r < 4; r++) {
            float e = expf(sc[ct][r] - m);
            sc[ct][r] = e;
            s += e;
        }
    s += __shfl_xor(s, 16, 64);
    s += __shfl_xor(s, 32, 64);
    float inv = 1.f / s;
    int q = qt * 64 + wave * 16 + lr;
    if (q < QL) {
        float* Pp = P + ((long)(b * HEADS + h)) * VS * QL + q;
#pragma unroll
        for (int ct = 0; ct < 13; ct++)
#pragma unroll
            for (int r = 0; r < 4; r++) {
                int n = ct * 16 + kg * 4 + r;
                if (n < VS) Pp[(long)n * QL] = sc[ct][r] * inv;
            }
    }
}

// ---------------- fused conv v8: v7 structure + hoisted bpermute + pointer-walk prefetch ----
// Edge-lane bpermute garbage is harmless: lane0/63 g values only feed non-output lanes;
// zero-padding of h/h1 is enforced by qm (multiplicative) + uniform N-range guards.
#define CSTEP8(N, PS, TAw,TAm2, TBw,TBm1, UAw,UAm2, UBw,UBm1)                      \
{                                                                                  \
    f32x2 vn = vcol2[(N)];                                                         \
    float psm = (PS) * qm;                                                         \
    f32x2 pv; pv.x = psm * vn.x; pv.y = psm * vn.y;                                \
    f32x2 hm, hp;                                                                  \
    hm.x = bperm(upidx, pv.x); hm.y = bperm(upidx, pv.y);                          \
    hp.x = bperm(dnidx, pv.x); hp.y = bperm(dnidx, pv.y);                          \
    f32x2 g = z2;                                                                  \
    if ((N) >= 1 && (N) <= VS) {                                                   \
        f32x2 tC = pk_fma(hp, w1p[8], pk_fma(pv, w1p[7], pk_mul(hm, w1p[6])));     \
        f32x2 sg = pk_add(pk_add(tC, TBm1), pk_add(TAm2, b1v2));                   \
        g = pk_mul(pk_max0(sg), qm2);                                              \
    }                                                                              \
    TAw = pk_fma(hp, w1p[2], pk_fma(pv, w1p[1], pk_mul(hm, w1p[0])));              \
    TBw = pk_fma(hp, w1p[5], pk_fma(pv, w1p[4], pk_mul(hm, w1p[3])));              \
    f32x2 gm, gp;                                                                  \
    gm.x = bperm(upidx, g.x); gm.y = bperm(upidx, g.y);                            \
    gp.x = bperm(dnidx, g.x); gp.y = bperm(dnidx, g.y);                            \
    if ((N) >= alo && (N) <= ahi) {                                                \
        f32x2 uC = pk_fma(gp, w2p[8], pk_fma(g, w2p[7], pk_mul(gm, w2p[6])));      \
        f32x2 s2 = pk_add(pk_add(uC, UBm1), pk_add(UAm2, b2v2));                   \
        csum = pk_add(csum, pk_max0(s2));                                          \
    }                                                                              \
    UAw = pk_fma(gp, w2p[2], pk_fma(g, w2p[1], pk_mul(gm, w2p[0])));               \
    UBw = pk_fma(gp, w2p[5], pk_fma(g, w2p[4], pk_mul(gm, w2p[3])));               \
}

#define CBODY(N0, S0, S1, S2)                                                      \
    CSTEP8(N0,     S0, tAa,tAb, tBa,tBc, uAa,uAb, uBa,uBc)                         \
    CSTEP8((N0)+1, S1, tAb,tAc, tBb,tBa, uAb,uAc, uBb,uBa)                         \
    CSTEP8((N0)+2, S2, tAc,tAa, tBc,tBb, uAc,uAa, uBc,uBb)

__global__ __launch_bounds__(256) void conv_pk_kernel(
    const float* __restrict__ P, const float* __restrict__ vs,
    const float* __restrict__ dw1, const float* __restrict__ dw2,
    const float* __restrict__ bn1g, const float* __restrict__ bn1b,
    const float* __restrict__ bn1m, const float* __restrict__ bn1v,
    const float* __restrict__ bn2g, const float* __restrict__ bn2b,
    const float* __restrict__ bn2m, const float* __restrict__ bn2v,
    float* __restrict__ m2a, float* __restrict__ m2b1, float* __restrict__ m2b2) {
    int bc = blockIdx.x;            // 2048 = b(4) x cpair(256) x half(2)
    int half = bc & 1;
    int c0 = ((bc >> 1) & 255) * 2;
    int b = bc >> 9;
    int h = c0 >> 6;
    const int no  = half ? 96 : 0;
    const int alo = half ? 100 : 2;
    const int ahi = half ? 197 : 99;
    int tid = threadIdx.x;
    int wave = tid >> 6, lane = tid & 63;
    int q = wave * 60 + lane - 2;
    bool outok = (lane >= 2 && lane <= 61 && q < QL);
    float qm = (q >= 0 && q < QL) ? 1.f : 0.f;
    f32x2 qm2; qm2.x = qm; qm2.y = qm;
    int qc = min(max(q, 0), QL - 1);
    const int upidx = ((lane - 1) & 63) << 2;
    const int dnidx = ((lane + 1) & 63) << 2;
    __shared__ __align__(8) f32x2 vcol2[200];   // zero-padded past VS
    if (tid < 200) {
        f32x2 t = {0.f, 0.f};
        if (tid < VS) {
            const float* vp = vs + ((long)(b * VS + tid)) * DIM + c0;
            t.x = vp[0]; t.y = vp[1];
        }
        vcol2[tid] = t;
    }
    float s1x = bn1g[c0]     * rsqrtf(bn1v[c0]     + EPS_BN);
    float s1y = bn1g[c0 + 1] * rsqrtf(bn1v[c0 + 1] + EPS_BN);
    float s2x = bn2g[c0]     * rsqrtf(bn2v[c0]     + EPS_BN);
    float s2y = bn2g[c0 + 1] * rsqrtf(bn2v[c0 + 1] + EPS_BN);
    f32x2 b1v2; b1v2.x = bn1b[c0] - bn1m[c0] * s1x; b1v2.y = bn1b[c0 + 1] - bn1m[c0 + 1] * s1y;
    f32x2 b2v2; b2v2.x = bn2b[c0] - bn2m[c0] * s2x; b2v2.y = bn2b[c0 + 1] - bn2m[c0 + 1] * s2y;
    f32x2 w1p[9], w2p[9];
#pragma unroll
    for (int i = 0; i < 9; i++) {
        w1p[i].x = dw1[c0 * 9 + i] * s1x;       w1p[i].y = dw1[(c0 + 1) * 9 + i] * s1y;
        w2p[i].x = dw2[c0 * 9 + i] * s2x;       w2p[i].y = dw2[(c0 + 1) * 9 + i] * s2y;
    }
    const float* Pp = P + ((long)(b * HEADS + h)) * VS * QL;
    const float* pqb = Pp + qc;               // clamped per-lane column pointer
    __syncthreads();
    const f32x2 z2 = {0.f, 0.f};
    f32x2 tAa = z2, tAb = z2, tAc = z2, tBa = z2, tBb = z2, tBc = z2;
    f32x2 uAa = z2, uAb = z2, uAc = z2, uBa = z2, uBb = z2, uBc = z2;
    f32x2 csum = z2;
    float ps0 = pqb[(long)(no + 0) * QL];
    float ps1 = pqb[(long)(no + 1) * QL];
    float ps2v = pqb[(long)(no + 2) * QL];
    const float* pq = pqb + (long)(no + 3) * QL;
    // 32 bodies with unguarded pointer-walk prefetch (rows <= no+98 <= 194, always valid)
    for (int k = 0; k < 32; k++) {
        float pn0 = pq[0];
        float pn1 = pq[QL];
        float pn2 = pq[2 * QL];
        int N0 = no + k * 3;
        CBODY(N0, ps0, ps1, ps2v)
        ps0 = pn0; ps1 = pn1; ps2v = pn2;
        pq += 3 * QL;
    }
    // tail: rows no+99..101 may exceed VS -> guarded one-time loads
    float pt0 = (no + 99  < VS) ? pq[0]      : 0.f;
    float pt1 = (no + 100 < VS) ? pq[QL]     : 0.f;
    float pt2 = (no + 101 < VS) ? pq[2 * QL] : 0.f;
    { int N0 = no + 96; CBODY(N0, ps0, ps1, ps2v) }
    ps0 = pt0; ps1 = pt1; ps2v = pt2;
    { int N0 = no + 99; CBODY(N0, ps0, ps1, ps2v) }
    if (outok) {
        const float inv = 1.f / (float)VS;
        f32x2 o; o.x = csum.x * inv; o.y = csum.y * inv;
        int row = b * QL + q;
        if (!half) {
            *(f32x2*)&m2a[(long)row * 512 + c0] = o;
        } else {
            float* dst = (row < 784) ? (m2b1 + (long)row * 512) : (m2b2 + (long)(row - 784) * 512);
            *(f32x2*)&dst[c0] = o;
        }
    }
}

// ---------------- attention 2 via MFMA (R10-proven) ----------------
__global__ __launch_bounds__(256) void attn2_mfma(const float* __restrict__ Qm,
                                                  const float* __restrict__ Km,
                                                  const float* __restrict__ Vm,
                                                  float* __restrict__ O) {
    int bid = blockIdx.x;          // 128 = b(4) x h(8) x nq(4)
    int nq = bid & 3;
    int h = (bid >> 2) & 7;
    int b = bid >> 5;
    int n0 = nq * 64;
    int tid = threadIdx.x;
    int wave = tid >> 6, lane = tid & 63;
    int lr = lane & 15, kg = lane >> 4;

    __shared__ __align__(16) char smem[77568];
    ushort (*VT)[264] = (ushort(*)[264])smem;            // [64][264]  VT[d][q]
    ushort (*Qb)[72]  = (ushort(*)[72])(smem + 33792);   // [64][72]
    ushort (*Kb)[72]  = (ushort(*)[72])(smem + 43008);   // [240][72]
    ushort (*Pl)[264] = (ushort(*)[264])(smem + 33792);  // [64][264] aliases Qb/Kb

    const long qmBase = ((long)(b * VS)) * DIM + h * 64;
    const long kmBase = ((long)(b * QL)) * DIM + h * 64;

    {
        int r = tid >> 2, c0 = (tid & 3) * 16;
        int n = min(n0 + r, VS - 1);
        const float* src = Qm + qmBase + (long)n * DIM + c0;
        *(uint4*)&Qb[r][c0]     = ld_cvt8(src);
        *(uint4*)&Qb[r][c0 + 8] = ld_cvt8(src + 8);
    }
    {
        int c0 = (tid & 3) * 16;
#pragma unroll
        for (int i = 0; i < 4; i++) {
            int r = (tid >> 2) + 64 * i;
            if (r < 240) {
                uint4 lo = {0u,0u,0u,0u}, hi = {0u,0u,0u,0u};
                if (r < QL) {
                    const float* src = Km + kmBase + (long)r * DIM + c0;
                    lo = ld_cvt8(src); hi = ld_cvt8(src + 8);
                }
                *(uint4*)&Kb[r][c0]     = lo;
                *(uint4*)&Kb[r][c0 + 8] = hi;
            }
        }
    }
    {
        int c0 = (tid & 3) * 16;
#pragma unroll
        for (int i = 0; i < 4; i++) {
            int qq = (tid >> 2) + 64 * i;
            if (qq < 240) {
                ushort u[16];
                if (qq < QL) {
                    const float* src = Vm + kmBase + (long)qq * DIM + c0;
                    *(uint4*)&u[0] = ld_cvt8(src);
                    *(uint4*)&u[8] = ld_cvt8(src + 8);
                } else {
#pragma unroll
                    for (int j = 0; j < 16; j++) u[j] = 0;
                }
#pragma unroll
                for (int j = 0; j < 16; j++) VT[c0 + j][qq] = u[j];
            }
        }
        int d = tid >> 2, qz = 240 + (tid & 3) * 4;
#pragma unroll
        for (int j = 0; j < 4; j++) VT[d][qz + j] = 0;
    }
    __syncthreads();

    bf16x8 a0 = *(const bf16x8*)&Qb[wave * 16 + lr][kg * 8];
    bf16x8 a1 = *(const bf16x8*)&Qb[wave * 16 + lr][32 + kg * 8];
    f32x4 sc[15];
#pragma unroll
    for (int ct = 0; ct < 15; ct++) {
        bf16x8 b0 = *(const bf16x8*)&Kb[ct * 16 + lr][kg * 8];
        bf16x8 b1 = *(const bf16x8*)&Kb[ct * 16 + lr][32 + kg * 8];
        f32x4 z = {0.f, 0.f, 0.f, 0.f};
        z = __builtin_amdgcn_mfma_f32_16x16x32_bf16(a0, b0, z, 0, 0, 0);
        z = __builtin_amdgcn_mfma_f32_16x16x32_bf16(a1, b1, z, 0, 0, 0);
        sc[ct] = z;
    }
    __syncthreads();

    const float scl = 0.044194173824159216f;
    float pinv[4];
#pragma unroll
    for (int r = 0; r < 4; r++) {
        float m = -1e30f;
#pragma unroll
        for (int ct = 0; ct < 15; ct++) {
            float v = sc[ct][r] * scl;
            if (ct * 16 + lr >= QL) v = -1e30f;
            sc[ct][r] = v;
            m = fmaxf(m, v);
        }
#pragma unroll
        for (int o = 1; o < 16; o <<= 1) m = fmaxf(m, __shfl_xor(m, o, 64));
        float s = 0.f;
#pragma unroll
        for (int ct = 0; ct < 15; ct++) {
            float e = expf(sc[ct][r] - m);
            sc[ct][r] = e;
            s += e;
        }
#pragma unroll
        for (int o = 1; o < 16; o <<= 1) s += __shfl_xor(s, o, 64);
        pinv[r] = 1.f / s;
    }
#pragma unroll
    for (int r = 0; r < 4; r++) {
        int row = wave * 16 + (lane >> 4) * 4 + r;
#pragma unroll
        for (int ct = 0; ct < 15; ct++) {
            float p = sc[ct][r] * pinv[r];
            Pl[row][ct * 16 + lr] = (ushort)(cvt_pk_bf16(p, p) & 0xffffu);
        }
        Pl[row][240 + lr] = 0;
    }
    __syncthreads();

    bf16x8 pa[8];
#pragma unroll
    for (int ks = 0; ks < 8; ks++)
        pa[ks] = *(const bf16x8*)&Pl[wave * 16 + lr][ks * 32 + kg * 8];
    f32x4 ov[4] = {};
#pragma unroll
    for (int dt = 0; dt < 4; dt++)
#pragma unroll
        for (int ks = 0; ks < 8; ks++) {
            bf16x8 vb = *(const bf16x8*)&VT[dt * 16 + lr][ks * 32 + kg * 8];
            ov[dt] = __builtin_amdgcn_mfma_f32_16x16x32_bf16(pa[ks], vb, ov[dt], 0, 0, 0);
        }

#pragma unroll
    for (int dt = 0; dt < 4; dt++)
#pragma unroll
        for (int r = 0; r < 4; r++) {
            int n = n0 + wave * 16 + (lane >> 4) * 4 + r;
            if (n < VS) {
                long addr = qmBase + (long)n * DIM + dt * 16 + lr;
                O[addr] = Qm[addr] + ov[dt][r];
            }
        }
}

static inline GJob mkjob(const float* A, int aRows, long aBS, long aOff,
                         const float* W, const float* bias,
                         const float* Add, int addRows, long addBS, long addOff,
                         float* Out, int M, float scale, int relu,
                         const float* A2lo = nullptr, const float* A2hi = nullptr,
                         int a2split = 0) {
    GJob j;
    j.A = A; j.W = W; j.bias = bias; j.Add = Add; j.Out = Out;
    j.A2lo = A2lo; j.A2hi = A2hi;
    j.aBS = aBS; j.aOff = aOff; j.addBS = addBS; j.addOff = addOff;
    j.aRows = aRows; j.addRows = addRows; j.M = M; j.relu = relu;
    j.scale = scale; j.a2split = a2split; j.pad1 = j.pad2 = 0;
    return j;
}

extern "C" void kernel_launch(void* const* d_in, const int* in_sizes, int n_in,
                              void* d_out, int out_size, void* d_ws, size_t ws_size,
                              hipStream_t stream) {
    const float* x     = (const float*)d_in[0];
    const float* Wq    = (const float*)d_in[1];
    const float* Wk    = (const float*)d_in[2];
    const float* Wv    = (const float*)d_in[3];
    const float* Wproj = (const float*)d_in[4];
    const float* bproj = (const float*)d_in[5];
    const float* dw1   = (const float*)d_in[6];
    const float* dw2   = (const float*)d_in[7];
    const float* pw    = (const float*)d_in[8];
    const float* bn1g  = (const float*)d_in[9];
    const float* bn1b  = (const float*)d_in[10];
    const float* bn1m  = (const float*)d_in[11];
    const float* bn1v  = (const float*)d_in[12];
    const float* bn2g  = (const float*)d_in[13];
    const float* bn2b  = (const float*)d_in[14];
    const float* bn2m  = (const float*)d_in[15];
    const float* bn2v  = (const float*)d_in[16];
    const float* mWq   = (const float*)d_in[17];
    const float* mbq   = (const float*)d_in[18];
    const float* mWk   = (const float*)d_in[19];
    const float* mbk   = (const float*)d_in[20];
    const float* mWv   = (const float*)d_in[21];
    const float* mbv   = (const float*)d_in[22];
    const float* mWo   = (const float*)d_in[23];
    const float* mbo   = (const float*)d_in[24];

    float* ws = (float*)d_ws;
    // Overlay (floats):
    //   qs @ 0 (460800) -> m2a -> Km
    //   ks @ 460800 (401408) -> m2b1 -> O
    //   vsb @ 862208 (401408) -> O2
    //   P @ 1263616 (1411200) -> [kc @ +0 | Qm @ +460800 | Vm @ +862208]
    //   m2b2 = d_out scratch (rows 784..899 of half-1 partials; consumed by L2, overwritten by L5)
    float* qs = ws;
    float* ks = ws + 460800;
    float* vsb = ws + 862208;
    float* P  = ws + 1263616;
    float* m2a = ws;            // reuses qs
    float* m2b1 = ws + 460800;  // reuses ks
    float* m2b2 = (float*)d_out;
    float* kc = ws + 1263616;
    float* Qm = ws + 1263616 + 460800;
    float* Vm = ws + 1263616 + 460800 + 401408;
    float* Km = ws;
    float* O  = ws + 460800;
    float* O2 = ws + 862208;

    const long xBS = 421L * DIM;
    const long clsOff = 196L * DIM;

    dim3 blk(256);

    // L1: q,k,v projections fused (360 blocks)
    {
        GJobs js;
        js.j[0] = mkjob(x, QL, xBS, clsOff, Wq, nullptr, nullptr, 1, 0, 0, qs, 900, 0.125f, 0);
        js.j[1] = mkjob(x, VS, xBS, 0, Wk, nullptr, nullptr, 1, 0, 0, ks, 784, 1.f, 0);
        js.j[2] = mkjob(x, VS, xBS, 0, Wv, nullptr, nullptr, 1, 0, 0, vsb, 784, 1.f, 0);
        js.j[3] = js.j[0];
        gemm_multi<0><<<dim3(8, 15, 3), blk, 0, stream>>>(js);
    }
    attn1_mfma<<<BATCH * HEADS * 4, blk, 0, stream>>>(qs, ks, P);
    conv_pk_kernel<<<2048, blk, 0, stream>>>(P, vsb, dw1, dw2,
                                             bn1g, bn1b, bn1m, bn1v,
                                             bn2g, bn2b, bn2m, bn2v, m2a, m2b1, m2b2);
    // L2: kc = cls_cat + (m2a+m2b) @ pw^T  AND  Qm = x_sem @ mWq^T + mbq
    {
        GJobs js;
        js.j[0] = mkjob(m2a, 900, 0, 0, pw, nullptr, x, QL, xBS, clsOff, kc, 900, 1.f, 0,
                        m2b1, m2b2, 784);
        js.j[1] = mkjob(x, VS, xBS, 0, mWq, mbq, nullptr, 1, 0, 0, Qm, 784, 1.f, 0);
        js.j[2] = js.j[3] = js.j[0];
        gemm_multi<1><<<dim3(8, 15, 2), blk, 0, stream>>>(js);
    }
    // L3: Km, Vm off kc
    {
        GJobs js;
        js.j[0] = mkjob(kc, 900, 0, 0, mWk, mbk, nullptr, 1, 0, 0, Km, 900, 1.f, 0);
        js.j[1] = mkjob(kc, 900, 0, 0, mWv, mbv, nullptr, 1, 0, 0, Vm, 900, 1.f, 0);
        js.j[2] = js.j[3] = js.j[0];
        gemm_multi<2><<<dim3(8, 15, 2), blk, 0, stream>>>(js);
    }
    attn2_mfma<<<BATCH * HEADS * 4, blk, 0, stream>>>(Qm, Km, Vm, O);
    // L4: O2 = O + relu(O @ mWo^T + mbo)
    {
        GJobs js;
        js.j[0] = mkjob(O, 784, 0, 0, mWo, mbo, O, 784, 0, 0, O2, 784, 1.f, 1);
        js.j[1] = js.j[2] = js.j[3] = js.j[0];
        gemm_multi<3><<<dim3(8, 13, 1), blk, 0, stream>>>(js);
    }
    // L5: out = O2 @ Wproj^T + bproj
    {
        GJobs js;
        js.j[0] = mkjob(O2, 784, 0, 0, Wproj, bproj, nullptr, 1, 0, 0, (float*)d_out, 784, 1.f, 0);
        js.j[1] = js.j[2] = js.j[3] = js.j[0];
        gemm_multi<4><<<dim3(8, 13, 1), blk, 0, stream>>>(js);
    }
}

// Round 15
// 159.512 us; speedup vs baseline: 2.2847x; 1.2989x over previous
//
#include <hip/hip_runtime.h>
#include <math.h>

#define DIM 512
#define HEADS 8
#define QL 225
#define VS 196
#define BATCH 4
#define EPS_BN 1e-5f

typedef __attribute__((ext_vector_type(8))) short bf16x8;
typedef __attribute__((ext_vector_type(4))) float f32x4;
typedef __attribute__((ext_vector_type(2))) float f32x2;

// ---------------- packed fp32 ops: native vector ops (compiler selects v_pk_*) ----------------
__device__ __forceinline__ f32x2 pk_fma(f32x2 a, f32x2 b, f32x2 c) {
    return __builtin_elementwise_fma(a, b, c);
}
__device__ __forceinline__ f32x2 pk_mul(f32x2 a, f32x2 b) { return a * b; }
__device__ __forceinline__ f32x2 pk_add(f32x2 a, f32x2 b) { return a + b; }
__device__ __forceinline__ f32x2 pk_max0(f32x2 a) {
    f32x2 z = {0.f, 0.f};
    return __builtin_elementwise_max(a, z);
}
// raw cross-lane pull (index hoisted by caller; edge lanes read garbage -- harmless by design)
__device__ __forceinline__ float bperm(int idx, float v) {
    return __int_as_float(__builtin_amdgcn_ds_bpermute(idx, __float_as_int(v)));
}

// ---------------- fp32 -> bf16 pack helpers ----------------
__device__ __forceinline__ unsigned cvt_pk_bf16(float lo, float hi) {
    unsigned r;
    asm("v_cvt_pk_bf16_f32 %0, %1, %2" : "=v"(r) : "v"(lo), "v"(hi));
    return r;
}
__device__ __forceinline__ uint4 ld_cvt8(const float* p) {
    float4 x = *(const float4*)p;
    float4 y = *(const float4*)(p + 4);
    uint4 r;
    r.x = cvt_pk_bf16(x.x, x.y);
    r.y = cvt_pk_bf16(x.z, x.w);
    r.z = cvt_pk_bf16(y.x, y.y);
    r.w = cvt_pk_bf16(y.z, y.w);
    return r;
}
__device__ __forceinline__ uint4 ld_cvt8s(const float* p, const float* p2) {
    float4 x = *(const float4*)p;
    float4 y = *(const float4*)(p + 4);
    if (p2) {
        float4 x2 = *(const float4*)p2;
        float4 y2 = *(const float4*)(p2 + 4);
        x.x += x2.x; x.y += x2.y; x.z += x2.z; x.w += x2.w;
        y.x += y2.x; y.y += y2.y; y.z += y2.z; y.w += y2.w;
    }
    uint4 r;
    r.x = cvt_pk_bf16(x.x, x.y);
    r.y = cvt_pk_bf16(x.z, x.w);
    r.z = cvt_pk_bf16(y.x, y.y);
    r.w = cvt_pk_bf16(y.z, y.w);
    return r;
}

// ---------------- multi-job bf16-MFMA GEMM (N=K=512): Out = scale*(A[+A2])@W^T (+bias)(relu)(+Add) ----
// v2: 32x32 tiles (4x block count vs 64x64) -- the GEMMs are latency-bound at ~1 block/CU;
// TLP, not per-block pipelining, hides the K-chain (R8 lesson).
struct GJob {
    const float* A; const float* W; const float* bias; const float* Add; float* Out;
    const float* A2lo; const float* A2hi;
    long aBS, aOff, addBS, addOff;
    int aRows, addRows, M, relu;
    float scale; int a2split; int pad1, pad2;
};
struct GJobs { GJob j[4]; };

template<int LAYER>
__global__ __launch_bounds__(256) void gemm_multi(GJobs jobs) {
    const GJob J = jobs.j[blockIdx.z];
    const int bm = blockIdx.y * 32, bn = blockIdx.x * 32;
    if (bm >= J.M) return;
    __shared__ __align__(16) ushort As[32][72];
    __shared__ __align__(16) ushort Bs[32][72];
    const int tid = threadIdx.x;
    const int srow = tid >> 3, skq = tid & 7;   // row 0..31, 8-float k-chunk 0..7
    const float *ap = nullptr, *ap2 = nullptr;
    {
        int m0 = bm + srow;
        if (m0 < J.M) {
            int bb = m0 / J.aRows; int r = m0 - bb * J.aRows;
            ap = J.A + bb * J.aBS + J.aOff + (long)r * 512 + skq * 8;
            if (J.A2lo) {
                ap2 = (m0 < J.a2split ? J.A2lo + (long)m0 * 512
                                      : J.A2hi + (long)(m0 - J.a2split) * 512) + skq * 8;
            }
        }
    }
    const float* bp = J.W + (long)(bn + srow) * 512 + skq * 8;

    const int lane = tid & 63, wid = tid >> 6;
    const int wr = wid >> 1, wc = wid & 1;      // 2x2 wave grid of 16x16 quadrants
    const int lr = lane & 15, kg = lane >> 4;

    f32x4 acc = {};

    uint4 a01 = {0u,0u,0u,0u};
    if (ap) a01 = ld_cvt8s(ap, ap2);
    uint4 b01 = ld_cvt8(bp);

    for (int kt = 0; kt < 512; kt += 64) {
        __syncthreads();
        *(uint4*)&As[srow][skq * 8] = a01;
        *(uint4*)&Bs[srow][skq * 8] = b01;
        __syncthreads();
        if (kt + 64 < 512) {
            if (ap) a01 = ld_cvt8s(ap + kt + 64, ap2 ? ap2 + kt + 64 : nullptr);
            b01 = ld_cvt8(bp + kt + 64);
        }
        bf16x8 a0 = *(const bf16x8*)&As[wr * 16 + lr][kg * 8];
        bf16x8 a1 = *(const bf16x8*)&As[wr * 16 + lr][32 + kg * 8];
        bf16x8 b0 = *(const bf16x8*)&Bs[wc * 16 + lr][kg * 8];
        bf16x8 b1 = *(const bf16x8*)&Bs[wc * 16 + lr][32 + kg * 8];
        acc = __builtin_amdgcn_mfma_f32_16x16x32_bf16(a0, b0, acc, 0, 0, 0);
        acc = __builtin_amdgcn_mfma_f32_16x16x32_bf16(a1, b1, acc, 0, 0, 0);
    }

#pragma unroll
    for (int r = 0; r < 4; r++) {
        int m = bm + wr * 16 + kg * 4 + r;
        if (m >= J.M) continue;
        const float* addrow = nullptr;
        if (J.Add) {
            int bb2 = m / J.addRows; int rr = m - bb2 * J.addRows;
            addrow = J.Add + bb2 * J.addBS + J.addOff + (long)rr * 512;
        }
        int n = bn + wc * 16 + lr;
        float v = acc[r] * J.scale;
        if (J.bias) v += J.bias[n];
        if (J.relu) v = fmaxf(v, 0.f);
        if (addrow) v += addrow[n];
        J.Out[(long)m * 512 + n] = v;
    }
}

// ---------------- attention 1 via MFMA (R13-proven): P^T[n][q] = softmax_n(q·k) ----
__global__ __launch_bounds__(256) void attn1_mfma(const float* __restrict__ qs,
                                                  const float* __restrict__ ks,
                                                  float* __restrict__ P) {
    int bid = blockIdx.x;          // 128 = b(4) x h(8) x qt(4)
    int qt = bid & 3;
    int h = (bid >> 2) & 7;
    int b = bid >> 5;
    int tid = threadIdx.x;
    int wave = tid >> 6, lane = tid & 63;
    int lr = lane & 15, kg = lane >> 4;
    __shared__ __align__(16) ushort Kb[208][72];
    __shared__ __align__(16) ushort Qb[64][72];
    const long qBase = ((long)(b * QL)) * DIM + h * 64;
    const long kBase = ((long)(b * VS)) * DIM + h * 64;
    {
        int r = tid >> 2, c0 = (tid & 3) * 16;
        int q = qt * 64 + r;
        uint4 lo = {0u,0u,0u,0u}, hi = {0u,0u,0u,0u};
        if (q < QL) {
            const float* s = qs + qBase + (long)q * DIM + c0;
            lo = ld_cvt8(s); hi = ld_cvt8(s + 8);
        }
        *(uint4*)&Qb[r][c0] = lo; *(uint4*)&Qb[r][c0 + 8] = hi;
    }
    {
        int c0 = (tid & 3) * 16;
#pragma unroll
        for (int i = 0; i < 4; i++) {
            int r = (tid >> 2) + 64 * i;
            if (r < 208) {
                uint4 lo = {0u,0u,0u,0u}, hi = {0u,0u,0u,0u};
                if (r < VS) {
                    const float* s = ks + kBase + (long)r * DIM + c0;
                    lo = ld_cvt8(s); hi = ld_cvt8(s + 8);
                }
                *(uint4*)&Kb[r][c0] = lo; *(uint4*)&Kb[r][c0 + 8] = hi;
            }
        }
    }
    __syncthreads();

    bf16x8 bq0 = *(const bf16x8*)&Qb[wave * 16 + lr][kg * 8];
    bf16x8 bq1 = *(const bf16x8*)&Qb[wave * 16 + lr][32 + kg * 8];
    f32x4 sc[13];
#pragma unroll
    for (int ct = 0; ct < 13; ct++) {
        bf16x8 a0 = *(const bf16x8*)&Kb[ct * 16 + lr][kg * 8];
        bf16x8 a1 = *(const bf16x8*)&Kb[ct * 16 + lr][32 + kg * 8];
        f32x4 z = {0.f, 0.f, 0.f, 0.f};
        z = __builtin_amdgcn_mfma_f32_16x16x32_bf16(a0, bq0, z, 0, 0, 0);
        z = __builtin_amdgcn_mfma_f32_16x16x32_bf16(a1, bq1, z, 0, 0, 0);
        sc[ct] = z;
    }
    float m = -1e30f;
#pragma unroll
    for (int ct = 0; ct < 13; ct++)
#pragma unroll
        for (int r = 0; r < 4; r++) {
            if (ct == 12 && kg > 0) sc[ct][r] = -1e30f;
            m = fmaxf(m, sc[ct][r]);
        }
    m = fmaxf(m, __shfl_xor(m, 16, 64));
    m = fmaxf(m, __shfl_xor(m, 32, 64));
    float s = 0.f;
#pragma unroll
    for (int ct = 0; ct < 13; ct++)
#pragma unroll
        for (int r = 0; r < 4; r++) {
            float e = expf(sc[ct][r] - m);
            sc[ct][r] = e;
            s += e;
        }
    s += __shfl_xor(s, 16, 64);
    s += __shfl_xor(s, 32, 64);
    float inv = 1.f / s;
    int q = qt * 64 + wave * 16 + lr;
    if (q < QL) {
        float* Pp = P + ((long)(b * HEADS + h)) * VS * QL + q;
#pragma unroll
        for (int ct = 0; ct < 13; ct++)
#pragma unroll
            for (int r = 0; r < 4; r++) {
                int n = ct * 16 + kg * 4 + r;
                if (n < VS) Pp[(long)n * QL] = sc[ct][r] * inv;
            }
    }
}

// ---------------- fused conv v9: v8 structure, native packed ops (no asm marshaling) ----
#define CSTEP8(N, PS, TAw,TAm2, TBw,TBm1, UAw,UAm2, UBw,UBm1)                      \
{                                                                                  \
    f32x2 vn = vcol2[(N)];                                                         \
    float psm = (PS) * qm;                                                         \
    f32x2 psm2 = {psm, psm};                                                       \
    f32x2 pv = pk_mul(psm2, vn);                                                   \
    f32x2 hm, hp;                                                                  \
    hm.x = bperm(upidx, pv.x); hm.y = bperm(upidx, pv.y);                          \
    hp.x = bperm(dnidx, pv.x); hp.y = bperm(dnidx, pv.y);                          \
    f32x2 g = z2;                                                                  \
    if ((N) >= 1 && (N) <= VS) {                                                   \
        f32x2 tC = pk_fma(hp, w1p[8], pk_fma(pv, w1p[7], pk_mul(hm, w1p[6])));     \
        f32x2 sg = pk_add(pk_add(tC, TBm1), pk_add(TAm2, b1v2));                   \
        g = pk_mul(pk_max0(sg), qm2);                                              \
    }                                                                              \
    TAw = pk_fma(hp, w1p[2], pk_fma(pv, w1p[1], pk_mul(hm, w1p[0])));              \
    TBw = pk_fma(hp, w1p[5], pk_fma(pv, w1p[4], pk_mul(hm, w1p[3])));              \
    f32x2 gm, gp;                                                                  \
    gm.x = bperm(upidx, g.x); gm.y = bperm(upidx, g.y);                            \
    gp.x = bperm(dnidx, g.x); gp.y = bperm(dnidx, g.y);                            \
    if ((N) >= alo && (N) <= ahi) {                                                \
        f32x2 uC = pk_fma(gp, w2p[8], pk_fma(g, w2p[7], pk_mul(gm, w2p[6])));      \
        f32x2 s2 = pk_add(pk_add(uC, UBm1), pk_add(UAm2, b2v2));                   \
        csum = pk_add(csum, pk_max0(s2));                                          \
    }                                                                              \
    UAw = pk_fma(gp, w2p[2], pk_fma(g, w2p[1], pk_mul(gm, w2p[0])));               \
    UBw = pk_fma(gp, w2p[5], pk_fma(g, w2p[4], pk_mul(gm, w2p[3])));               \
}

#define CBODY(N0, S0, S1, S2)                                                      \
    CSTEP8(N0,     S0, tAa,tAb, tBa,tBc, uAa,uAb, uBa,uBc)                         \
    CSTEP8((N0)+1, S1, tAb,tAc, tBb,tBa, uAb,uAc, uBb,uBa)                         \
    CSTEP8((N0)+2, S2, tAc,tAa, tBc,tBb, uAc,uAa, uBc,uBb)

__global__ __launch_bounds__(256) void conv_pk_kernel(
    const float* __restrict__ P, const float* __restrict__ vs,
    const float* __restrict__ dw1, const float* __restrict__ dw2,
    const float* __restrict__ bn1g, const float* __restrict__ bn1b,
    const float* __restrict__ bn1m, const float* __restrict__ bn1v,
    const float* __restrict__ bn2g, const float* __restrict__ bn2b,
    const float* __restrict__ bn2m, const float* __restrict__ bn2v,
    float* __restrict__ m2a, float* __restrict__ m2b1, float* __restrict__ m2b2) {
    int bc = blockIdx.x;            // 2048 = b(4) x cpair(256) x half(2)
    int half = bc & 1;
    int c0 = ((bc >> 1) & 255) * 2;
    int b = bc >> 9;
    int h = c0 >> 6;
    const int no  = half ? 96 : 0;
    const int alo = half ? 100 : 2;
    const int ahi = half ? 197 : 99;
    int tid = threadIdx.x;
    int wave = tid >> 6, lane = tid & 63;
    int q = wave * 60 + lane - 2;
    bool outok = (lane >= 2 && lane <= 61 && q < QL);
    float qm = (q >= 0 && q < QL) ? 1.f : 0.f;
    f32x2 qm2 = {qm, qm};
    int qc = min(max(q, 0), QL - 1);
    const int upidx = ((lane - 1) & 63) << 2;
    const int dnidx = ((lane + 1) & 63) << 2;
    __shared__ __align__(8) f32x2 vcol2[200];   // zero-padded past VS
    if (tid < 200) {
        f32x2 t = {0.f, 0.f};
        if (tid < VS) {
            const float* vp = vs + ((long)(b * VS + tid)) * DIM + c0;
            t.x = vp[0]; t.y = vp[1];
        }
        vcol2[tid] = t;
    }
    float s1x = bn1g[c0]     * rsqrtf(bn1v[c0]     + EPS_BN);
    float s1y = bn1g[c0 + 1] * rsqrtf(bn1v[c0 + 1] + EPS_BN);
    float s2x = bn2g[c0]     * rsqrtf(bn2v[c0]     + EPS_BN);
    float s2y = bn2g[c0 + 1] * rsqrtf(bn2v[c0 + 1] + EPS_BN);
    f32x2 b1v2 = {bn1b[c0] - bn1m[c0] * s1x, bn1b[c0 + 1] - bn1m[c0 + 1] * s1y};
    f32x2 b2v2 = {bn2b[c0] - bn2m[c0] * s2x, bn2b[c0 + 1] - bn2m[c0 + 1] * s2y};
    f32x2 w1p[9], w2p[9];
#pragma unroll
    for (int i = 0; i < 9; i++) {
        w1p[i].x = dw1[c0 * 9 + i] * s1x;       w1p[i].y = dw1[(c0 + 1) * 9 + i] * s1y;
        w2p[i].x = dw2[c0 * 9 + i] * s2x;       w2p[i].y = dw2[(c0 + 1) * 9 + i] * s2y;
    }
    const float* Pp = P + ((long)(b * HEADS + h)) * VS * QL;
    const float* pqb = Pp + qc;               // clamped per-lane column pointer
    __syncthreads();
    const f32x2 z2 = {0.f, 0.f};
    f32x2 tAa = z2, tAb = z2, tAc = z2, tBa = z2, tBb = z2, tBc = z2;
    f32x2 uAa = z2, uAb = z2, uAc = z2, uBa = z2, uBb = z2, uBc = z2;
    f32x2 csum = z2;
    float ps0 = pqb[(long)(no + 0) * QL];
    float ps1 = pqb[(long)(no + 1) * QL];
    float ps2v = pqb[(long)(no + 2) * QL];
    const float* pq = pqb + (long)(no + 3) * QL;
    // 32 bodies with unguarded pointer-walk prefetch (rows <= no+98 <= 194, always valid)
    for (int k = 0; k < 32; k++) {
        float pn0 = pq[0];
        float pn1 = pq[QL];
        float pn2 = pq[2 * QL];
        int N0 = no + k * 3;
        CBODY(N0, ps0, ps1, ps2v)
        ps0 = pn0; ps1 = pn1; ps2v = pn2;
        pq += 3 * QL;
    }
    // tail: rows no+99..101 may exceed VS -> guarded one-time loads
    float pt0 = (no + 99  < VS) ? pq[0]      : 0.f;
    float pt1 = (no + 100 < VS) ? pq[QL]     : 0.f;
    float pt2 = (no + 101 < VS) ? pq[2 * QL] : 0.f;
    { int N0 = no + 96; CBODY(N0, ps0, ps1, ps2v) }
    ps0 = pt0; ps1 = pt1; ps2v = pt2;
    { int N0 = no + 99; CBODY(N0, ps0, ps1, ps2v) }
    if (outok) {
        const float inv = 1.f / (float)VS;
        f32x2 o = csum * inv;
        int row = b * QL + q;
        if (!half) {
            *(f32x2*)&m2a[(long)row * 512 + c0] = o;
        } else {
            float* dst = (row < 784) ? (m2b1 + (long)row * 512) : (m2b2 + (long)(row - 784) * 512);
            *(f32x2*)&dst[c0] = o;
        }
    }
}

// ---------------- attention 2 via MFMA (R10-proven) ----------------
__global__ __launch_bounds__(256) void attn2_mfma(const float* __restrict__ Qm,
                                                  const float* __restrict__ Km,
                                                  const float* __restrict__ Vm,
                                                  float* __restrict__ O) {
    int bid = blockIdx.x;          // 128 = b(4) x h(8) x nq(4)
    int nq = bid & 3;
    int h = (bid >> 2) & 7;
    int b = bid >> 5;
    int n0 = nq * 64;
    int tid = threadIdx.x;
    int wave = tid >> 6, lane = tid & 63;
    int lr = lane & 15, kg = lane >> 4;

    __shared__ __align__(16) char smem[77568];
    ushort (*VT)[264] = (ushort(*)[264])smem;            // [64][264]  VT[d][q]
    ushort (*Qb)[72]  = (ushort(*)[72])(smem + 33792);   // [64][72]
    ushort (*Kb)[72]  = (ushort(*)[72])(smem + 43008);   // [240][72]
    ushort (*Pl)[264] = (ushort(*)[264])(smem + 33792);  // [64][264] aliases Qb/Kb

    const long qmBase = ((long)(b * VS)) * DIM + h * 64;
    const long kmBase = ((long)(b * QL)) * DIM + h * 64;

    {
        int r = tid >> 2, c0 = (tid & 3) * 16;
        int n = min(n0 + r, VS - 1);
        const float* src = Qm + qmBase + (long)n * DIM + c0;
        *(uint4*)&Qb[r][c0]     = ld_cvt8(src);
        *(uint4*)&Qb[r][c0 + 8] = ld_cvt8(src + 8);
    }
    {
        int c0 = (tid & 3) * 16;
#pragma unroll
        for (int i = 0; i < 4; i++) {
            int r = (tid >> 2) + 64 * i;
            if (r < 240) {
                uint4 lo = {0u,0u,0u,0u}, hi = {0u,0u,0u,0u};
                if (r < QL) {
                    const float* src = Km + kmBase + (long)r * DIM + c0;
                    lo = ld_cvt8(src); hi = ld_cvt8(src + 8);
                }
                *(uint4*)&Kb[r][c0]     = lo;
                *(uint4*)&Kb[r][c0 + 8] = hi;
            }
        }
    }
    {
        int c0 = (tid & 3) * 16;
#pragma unroll
        for (int i = 0; i < 4; i++) {
            int qq = (tid >> 2) + 64 * i;
            if (qq < 240) {
                ushort u[16];
                if (qq < QL) {
                    const float* src = Vm + kmBase + (long)qq * DIM + c0;
                    *(uint4*)&u[0] = ld_cvt8(src);
                    *(uint4*)&u[8] = ld_cvt8(src + 8);
                } else {
#pragma unroll
                    for (int j = 0; j < 16; j++) u[j] = 0;
                }
#pragma unroll
                for (int j = 0; j < 16; j++) VT[c0 + j][qq] = u[j];
            }
        }
        int d = tid >> 2, qz = 240 + (tid & 3) * 4;
#pragma unroll
        for (int j = 0; j < 4; j++) VT[d][qz + j] = 0;
    }
    __syncthreads();

    bf16x8 a0 = *(const bf16x8*)&Qb[wave * 16 + lr][kg * 8];
    bf16x8 a1 = *(const bf16x8*)&Qb[wave * 16 + lr][32 + kg * 8];
    f32x4 sc[15];
#pragma unroll
    for (int ct = 0; ct < 15; ct++) {
        bf16x8 b0 = *(const bf16x8*)&Kb[ct * 16 + lr][kg * 8];
        bf16x8 b1 = *(const bf16x8*)&Kb[ct * 16 + lr][32 + kg * 8];
        f32x4 z = {0.f, 0.f, 0.f, 0.f};
        z = __builtin_amdgcn_mfma_f32_16x16x32_bf16(a0, b0, z, 0, 0, 0);
        z = __builtin_amdgcn_mfma_f32_16x16x32_bf16(a1, b1, z, 0, 0, 0);
        sc[ct] = z;
    }
    __syncthreads();

    const float scl = 0.044194173824159216f;
    float pinv[4];
#pragma unroll
    for (int r = 0; r < 4; r++) {
        float m = -1e30f;
#pragma unroll
        for (int ct = 0; ct < 15; ct++) {
            float v = sc[ct][r] * scl;
            if (ct * 16 + lr >= QL) v = -1e30f;
            sc[ct][r] = v;
            m = fmaxf(m, v);
        }
#pragma unroll
        for (int o = 1; o < 16; o <<= 1) m = fmaxf(m, __shfl_xor(m, o, 64));
        float s = 0.f;
#pragma unroll
        for (int ct = 0; ct < 15; ct++) {
            float e = expf(sc[ct][r] - m);
            sc[ct][r] = e;
            s += e;
        }
#pragma unroll
        for (int o = 1; o < 16; o <<= 1) s += __shfl_xor(s, o, 64);
        pinv[r] = 1.f / s;
    }
#pragma unroll
    for (int r = 0; r < 4; r++) {
        int row = wave * 16 + (lane >> 4) * 4 + r;
#pragma unroll
        for (int ct = 0; ct < 15; ct++) {
            float p = sc[ct][r] * pinv[r];
            Pl[row][ct * 16 + lr] = (ushort)(cvt_pk_bf16(p, p) & 0xffffu);
        }
        Pl[row][240 + lr] = 0;
    }
    __syncthreads();

    bf16x8 pa[8];
#pragma unroll
    for (int ks = 0; ks < 8; ks++)
        pa[ks] = *(const bf16x8*)&Pl[wave * 16 + lr][ks * 32 + kg * 8];
    f32x4 ov[4] = {};
#pragma unroll
    for (int dt = 0; dt < 4; dt++)
#pragma unroll
        for (int ks = 0; ks < 8; ks++) {
            bf16x8 vb = *(const bf16x8*)&VT[dt * 16 + lr][ks * 32 + kg * 8];
            ov[dt] = __builtin_amdgcn_mfma_f32_16x16x32_bf16(pa[ks], vb, ov[dt], 0, 0, 0);
        }

#pragma unroll
    for (int dt = 0; dt < 4; dt++)
#pragma unroll
        for (int r = 0; r < 4; r++) {
            int n = n0 + wave * 16 + (lane >> 4) * 4 + r;
            if (n < VS) {
                long addr = qmBase + (long)n * DIM + dt * 16 + lr;
                O[addr] = Qm[addr] + ov[dt][r];
            }
        }
}

static inline GJob mkjob(const float* A, int aRows, long aBS, long aOff,
                         const float* W, const float* bias,
                         const float* Add, int addRows, long addBS, long addOff,
                         float* Out, int M, float scale, int relu,
                         const float* A2lo = nullptr, const float* A2hi = nullptr,
                         int a2split = 0) {
    GJob j;
    j.A = A; j.W = W; j.bias = bias; j.Add = Add; j.Out = Out;
    j.A2lo = A2lo; j.A2hi = A2hi;
    j.aBS = aBS; j.aOff = aOff; j.addBS = addBS; j.addOff = addOff;
    j.aRows = aRows; j.addRows = addRows; j.M = M; j.relu = relu;
    j.scale = scale; j.a2split = a2split; j.pad1 = j.pad2 = 0;
    return j;
}

extern "C" void kernel_launch(void* const* d_in, const int* in_sizes, int n_in,
                              void* d_out, int out_size, void* d_ws, size_t ws_size,
                              hipStream_t stream) {
    const float* x     = (const float*)d_in[0];
    const float* Wq    = (const float*)d_in[1];
    const float* Wk    = (const float*)d_in[2];
    const float* Wv    = (const float*)d_in[3];
    const float* Wproj = (const float*)d_in[4];
    const float* bproj = (const float*)d_in[5];
    const float* dw1   = (const float*)d_in[6];
    const float* dw2   = (const float*)d_in[7];
    const float* pw    = (const float*)d_in[8];
    const float* bn1g  = (const float*)d_in[9];
    const float* bn1b  = (const float*)d_in[10];
    const float* bn1m  = (const float*)d_in[11];
    const float* bn1v  = (const float*)d_in[12];
    const float* bn2g  = (const float*)d_in[13];
    const float* bn2b  = (const float*)d_in[14];
    const float* bn2m  = (const float*)d_in[15];
    const float* bn2v  = (const float*)d_in[16];
    const float* mWq   = (const float*)d_in[17];
    const float* mbq   = (const float*)d_in[18];
    const float* mWk   = (const float*)d_in[19];
    const float* mbk   = (const float*)d_in[20];
    const float* mWv   = (const float*)d_in[21];
    const float* mbv   = (const float*)d_in[22];
    const float* mWo   = (const float*)d_in[23];
    const float* mbo   = (const float*)d_in[24];

    float* ws = (float*)d_ws;
    // Overlay (floats):
    //   qs @ 0 (460800) -> m2a -> Km
    //   ks @ 460800 (401408) -> m2b1 -> O
    //   vsb @ 862208 (401408) -> O2
    //   P @ 1263616 (1411200) -> [kc @ +0 | Qm @ +460800 | Vm @ +862208]
    //   m2b2 = d_out scratch (rows 784..899 of half-1 partials; consumed by L2, overwritten by L5)
    float* qs = ws;
    float* ks = ws + 460800;
    float* vsb = ws + 862208;
    float* P  = ws + 1263616;
    float* m2a = ws;            // reuses qs
    float* m2b1 = ws + 460800;  // reuses ks
    float* m2b2 = (float*)d_out;
    float* kc = ws + 1263616;
    float* Qm = ws + 1263616 + 460800;
    float* Vm = ws + 1263616 + 460800 + 401408;
    float* Km = ws;
    float* O  = ws + 460800;
    float* O2 = ws + 862208;

    const long xBS = 421L * DIM;
    const long clsOff = 196L * DIM;

    dim3 blk(256);

    // L1: q,k,v projections fused (16x29x3 = 1392 blocks)
    {
        GJobs js;
        js.j[0] = mkjob(x, QL, xBS, clsOff, Wq, nullptr, nullptr, 1, 0, 0, qs, 900, 0.125f, 0);
        js.j[1] = mkjob(x, VS, xBS, 0, Wk, nullptr, nullptr, 1, 0, 0, ks, 784, 1.f, 0);
        js.j[2] = mkjob(x, VS, xBS, 0, Wv, nullptr, nullptr, 1, 0, 0, vsb, 784, 1.f, 0);
        js.j[3] = js.j[0];
        gemm_multi<0><<<dim3(16, 29, 3), blk, 0, stream>>>(js);
    }
    attn1_mfma<<<BATCH * HEADS * 4, blk, 0, stream>>>(qs, ks, P);
    conv_pk_kernel<<<2048, blk, 0, stream>>>(P, vsb, dw1, dw2,
                                             bn1g, bn1b, bn1m, bn1v,
                                             bn2g, bn2b, bn2m, bn2v, m2a, m2b1, m2b2);
    // L2: kc = cls_cat + (m2a+m2b) @ pw^T  AND  Qm = x_sem @ mWq^T + mbq
    {
        GJobs js;
        js.j[0] = mkjob(m2a, 900, 0, 0, pw, nullptr, x, QL, xBS, clsOff, kc, 900, 1.f, 0,
                        m2b1, m2b2, 784);
        js.j[1] = mkjob(x, VS, xBS, 0, mWq, mbq, nullptr, 1, 0, 0, Qm, 784, 1.f, 0);
        js.j[2] = js.j[3] = js.j[0];
        gemm_multi<1><<<dim3(16, 29, 2), blk, 0, stream>>>(js);
    }
    // L3: Km, Vm off kc
    {
        GJobs js;
        js.j[0] = mkjob(kc, 900, 0, 0, mWk, mbk, nullptr, 1, 0, 0, Km, 900, 1.f, 0);
        js.j[1] = mkjob(kc, 900, 0, 0, mWv, mbv, nullptr, 1, 0, 0, Vm, 900, 1.f, 0);
        js.j[2] = js.j[3] = js.j[0];
        gemm_multi<2><<<dim3(16, 29, 2), blk, 0, stream>>>(js);
    }
    attn2_mfma<<<BATCH * HEADS * 4, blk, 0, stream>>>(Qm, Km, Vm, O);
    // L4: O2 = O + relu(O @ mWo^T + mbo)
    {
        GJobs js;
        js.j[0] = mkjob(O, 784, 0, 0, mWo, mbo, O, 784, 0, 0, O2, 784, 1.f, 1);
        js.j[1] = js.j[2] = js.j[3] = js.j[0];
        gemm_multi<3><<<dim3(16, 25, 1), blk, 0, stream>>>(js);
    }
    // L5: out = O2 @ Wproj^T + bproj
    {
        GJobs js;
        js.j[0] = mkjob(O2, 784, 0, 0, Wproj, bproj, nullptr, 1, 0, 0, (float*)d_out, 784, 1.f, 0);
        js.j[1] = js.j[2] = js.j[3] = js.j[0];
        gemm_multi<4><<<dim3(16, 25, 1), blk, 0, stream>>>(js);
    }
}